// Round 18
// baseline (1911.089 us; speedup 1.0000x reference)
//
#include <hip/hip_runtime.h>
#include <cmath>

// ---------------------------------------------------------------------------
// VQ-VAE forward, round 18.
// r17 post-mortem: register prefetch = pure overhead (dispatch identical,
// VGPR 188->232) -- barrier drain is structural (guide §5); reverted.
// This round: occupancy attack. enc3/dec3 x-tile 4->2 (1024 blocks), acc
// 128->64 VGPR, __launch_bounds__(256,4) pins <=128 VGPR => 4 waves/SIMD
// (16 waves/CU, was 8): one block's barrier drain overlaps 3 others' compute.
// LDS 32.6KB enc / 16.3KB dec. All else = r16 (1663us best).
// ---------------------------------------------------------------------------

static constexpr int NPOS  = 131072;
static constexpr long long NELEM = 8388608;

typedef __attribute__((ext_vector_type(8))) short short8;
typedef __attribute__((ext_vector_type(8))) unsigned short ushort8;
typedef __attribute__((ext_vector_type(4))) float f32x4;

__device__ __forceinline__ unsigned short f2bf(float f) {
  unsigned int x = __float_as_uint(f);
  unsigned int r = (x + 0x7fffu + ((x >> 16) & 1u)) >> 16;
  return (unsigned short)r;
}
__device__ __forceinline__ float bf2f(unsigned short u) {
  return __uint_as_float(((unsigned int)u) << 16);
}
__device__ __forceinline__ void split2(float v, unsigned short& h, unsigned short& l) {
  unsigned short hh = f2bf(v);
  h = hh;
  l = f2bf(v - bf2f(hh));
}

// ======== enc_c1: 4x4 s2 p1 -> hi/lo in 4 PARITY planes (66x66x64 pad) =====
__global__ void __launch_bounds__(256) enc1_t(
    const float* __restrict__ in, const float* __restrict__ w,
    const float* __restrict__ bias,
    unsigned short* __restrict__ outh, unsigned short* __restrict__ outl)
{
  int tid = threadIdx.x;
  int wv = tid >> 6, lane = tid & 63;
  int rr = wv >> 1, px = wv & 1;
  int oy  = blockIdx.x * 2 + rr;
  int ox  = 2 * lane + px;
  int oc0 = blockIdx.y * 16;
  int b   = blockIdx.z;

  const float* pl = in + (size_t)b * 65536;
  float v[16];
  #pragma unroll
  for (int ky = 0; ky < 4; ++ky) {
    int iy = 2 * oy - 1 + ky;
    #pragma unroll
    for (int kx = 0; kx < 4; ++kx) {
      int ix = 2 * ox - 1 + kx;
      v[ky * 4 + kx] = (iy >= 0 && iy < 256 && ix >= 0 && ix < 256)
                       ? pl[iy * 256 + ix] : 0.f;
    }
  }
  float acc[16];
  #pragma unroll
  for (int o = 0; o < 16; ++o) acc[o] = bias[oc0 + o];
  #pragma unroll
  for (int t = 0; t < 16; ++t)
    #pragma unroll
    for (int o = 0; o < 16; ++o)
      acc[o] += v[t] * w[(size_t)(oc0 + o) * 16 + t];

  int pp = ((oy & 1) << 1) | px;
  int u = oy >> 1, vv = lane;
  size_t o = ((size_t)(b * 4 + pp)) * 278784
           + ((size_t)(u + 1) * 66 + (vv + 1)) * 64 + oc0;
  ushort8 h0, h1, l0, l1;
  #pragma unroll
  for (int k = 0; k < 8; ++k) {
    unsigned short hh, ll;
    split2(fmaxf(acc[k], 0.f), hh, ll);      h0[k] = hh; l0[k] = ll;
    split2(fmaxf(acc[k + 8], 0.f), hh, ll);  h1[k] = hh; l1[k] = ll;
  }
  *(ushort8*)(outh + o)     = h0;
  *(ushort8*)(outh + o + 8) = h1;
  *(ushort8*)(outl + o)     = l0;
  *(ushort8*)(outl + o + 8) = l1;
}

// ======== enc_c2 as 4 parity 2x2 convs, LDS-staged, CP=40 (r16) ============
__global__ void __launch_bounds__(256) mfma_enc2p(
    const unsigned short* __restrict__ inh, const unsigned short* __restrict__ inl,
    const unsigned short* __restrict__ wh, const unsigned short* __restrict__ wl,
    const float* __restrict__ bias,
    unsigned short* __restrict__ outh, unsigned short* __restrict__ outl)
{
  constexpr int IC = 64, OC = 128, OM = 8, CP = 40;
  __shared__ unsigned short sh[6 * 66 * CP];
  __shared__ unsigned short sl[6 * 66 * CP];
  const int out_ss = 4356 * OC;
  const int tid = threadIdx.x;
  const int wv = tid >> 6, lane = tid & 63;
  const int quad = lane >> 4, l15 = lane & 15;

  const int id = blockIdx.x;
  const int xcd = id & 7;
  const int slot = id >> 3;
  const int bi = slot >> 4;
  const int yb = slot & 15;
  const int b = bi * 8 + xcd;
  const int y0 = yb * 4;
  const int y = y0 + wv;

  int xs[4];
  #pragma unroll
  for (int j = 0; j < 4; ++j) xs[j] = j * 16 + l15;

  f32x4 acc[OM][4];
  #pragma unroll
  for (int m = 0; m < OM; ++m) {
    const int oc0 = m * 16 + quad * 4;
    float4 bs = *(const float4*)(bias + oc0);
    f32x4 ini;
    ini[0] = bs.x; ini[1] = bs.y; ini[2] = bs.z; ini[3] = bs.w;
    #pragma unroll
    for (int j = 0; j < 4; ++j) acc[m][j] = ini;
  }

  for (int k0 = 0; k0 < IC; k0 += 32) {
    #pragma unroll 1
    for (int pp = 0; pp < 4; ++pp) {
      const int py = pp >> 1, px = pp & 1;
      const unsigned short* pbh = inh + (size_t)(b * 4 + pp) * 278784;
      const unsigned short* pbl = inl + (size_t)(b * 4 + pp) * 278784;
      for (int idx = tid; idx < 1584; idx += 256) {
        int row = idx / 264;
        int rem = idx - row * 264;
        int col = rem >> 2;
        int v = (rem & 3) << 3;
        size_t g = ((size_t)(y0 + row) * 66 + col) * IC + k0 + v;
        int s = (row * 66 + col) * CP + v;
        *(ushort8*)&sh[s] = *(const ushort8*)(pbh + g);
        *(ushort8*)&sl[s] = *(const ushort8*)(pbl + g);
      }
      __syncthreads();

      #pragma unroll
      for (int a = 0; a < 2; ++a) {
        const int ky = py ? (2 * a) : (1 + 2 * a);
        const int du = py ? (a - 1) : a;
        #pragma unroll
        for (int c2 = 0; c2 < 2; ++c2) {
          const int kx = px ? (2 * c2) : (1 + 2 * c2);
          const int dv = px ? (c2 - 1) : c2;
          const int t = ky * 4 + kx;
          short8 bh4[4], bl4[4];
          #pragma unroll
          for (int j = 0; j < 4; ++j) {
            int s = ((wv + du + 1) * 66 + xs[j] + dv + 1) * CP + quad * 8;
            bh4[j] = *(const short8*)&sh[s];
            bl4[j] = *(const short8*)&sl[s];
          }
          const unsigned short* wrh = wh + (size_t)t * OC * IC + (size_t)l15 * IC + quad * 8 + k0;
          const unsigned short* wrl = wl + (size_t)t * OC * IC + (size_t)l15 * IC + quad * 8 + k0;
          #pragma unroll
          for (int m = 0; m < OM; ++m) {
            short8 ah = *(const short8*)(wrh + (size_t)m * 16 * IC);
            short8 al = *(const short8*)(wrl + (size_t)m * 16 * IC);
            #pragma unroll
            for (int j = 0; j < 4; ++j) {
              acc[m][j] = __builtin_amdgcn_mfma_f32_16x16x32_bf16(ah, bh4[j], acc[m][j], 0, 0, 0);
              acc[m][j] = __builtin_amdgcn_mfma_f32_16x16x32_bf16(ah, bl4[j], acc[m][j], 0, 0, 0);
              acc[m][j] = __builtin_amdgcn_mfma_f32_16x16x32_bf16(al, bh4[j], acc[m][j], 0, 0, 0);
            }
          }
        }
      }
      __syncthreads();
    }
  }

  #pragma unroll
  for (int m = 0; m < OM; ++m) {
    const int oc0 = m * 16 + quad * 4;
    #pragma unroll
    for (int j = 0; j < 4; ++j) {
      size_t o = (size_t)b * out_ss + ((size_t)(y + 1) * 66 + (xs[j] + 1)) * OC + oc0;
      ushort4 h4, l4;
      unsigned short hh, ll;
      float v;
      v = fmaxf(acc[m][j][0], 0.f); split2(v, hh, ll); h4.x = hh; l4.x = ll;
      v = fmaxf(acc[m][j][1], 0.f); split2(v, hh, ll); h4.y = hh; l4.y = ll;
      v = fmaxf(acc[m][j][2], 0.f); split2(v, hh, ll); h4.z = hh; l4.z = ll;
      v = fmaxf(acc[m][j][3], 0.f); split2(v, hh, ll); h4.w = hh; l4.w = ll;
      *(ushort4*)(outh + o) = h4;
      *(ushort4*)(outl + o) = l4;
    }
  }
}

// ======== bf16x3 3x3, LDS-staged, CP=40, 2 x-tiles, 16 waves/CU ============
// Block = 4 rows x 32 cols; grid 1024, swizzled. acc[8][2]=64 VGPR;
// __launch_bounds__(256,4) pins <=128 VGPR => 4 waves/SIMD.
template<int IC, int OC, bool BIAS, bool RELU>
__global__ void __launch_bounds__(256, 4) mfma_enc3(
    const unsigned short* __restrict__ inh, const unsigned short* __restrict__ inl,
    const unsigned short* __restrict__ wh, const unsigned short* __restrict__ wl,
    const float* __restrict__ bias,
    unsigned short* __restrict__ outh, unsigned short* __restrict__ outl)
{
  constexpr int OM = OC / 16;
  constexpr int CP = 40;
  __shared__ unsigned short sh[6 * 34 * CP];
  __shared__ unsigned short sl[6 * 34 * CP];
  const int in_ss  = 4356 * IC;
  const int out_ss = 4356 * OC;
  const int tid = threadIdx.x;
  const int wv = tid >> 6, lane = tid & 63;
  const int quad = lane >> 4, l15 = lane & 15;

  const int id = blockIdx.x;
  const int xcd = id & 7;
  const int slot = id >> 3;
  const int bi = slot >> 5;
  const int r = slot & 31;
  const int xb = r >> 4;
  const int yb = r & 15;
  const int b = bi * 8 + xcd;
  const int y0 = yb * 4;
  const int y = y0 + wv;
  const int xbase = xb * 32;

  int xsl[2];
  #pragma unroll
  for (int j = 0; j < 2; ++j) xsl[j] = j * 16 + l15;
  const unsigned short* ibh = inh + (size_t)b * in_ss;
  const unsigned short* ibl = inl + (size_t)b * in_ss;

  f32x4 acc[OM][2];
  #pragma unroll
  for (int m = 0; m < OM; ++m) {
    const int oc0 = m * 16 + quad * 4;
    f32x4 ini = {0.f, 0.f, 0.f, 0.f};
    if (BIAS) {
      float4 bs = *(const float4*)(bias + oc0);
      ini[0] = bs.x; ini[1] = bs.y; ini[2] = bs.z; ini[3] = bs.w;
    }
    #pragma unroll
    for (int j = 0; j < 2; ++j) acc[m][j] = ini;
  }

  for (int k0 = 0; k0 < IC; k0 += 32) {
    // stage 6 rows x 34 cols x 32ch (816 ushort8 slots, hi+lo)
    for (int idx = tid; idx < 816; idx += 256) {
      int row = idx / 136;
      int rem = idx - row * 136;
      int col = rem >> 2;
      int v = (rem & 3) << 3;
      size_t g = ((size_t)(y0 + row) * 66 + xbase + col) * IC + k0 + v;
      int s = (row * 34 + col) * CP + v;
      *(ushort8*)&sh[s] = *(const ushort8*)(ibh + g);
      *(ushort8*)&sl[s] = *(const ushort8*)(ibl + g);
    }
    __syncthreads();

    #pragma unroll
    for (int t = 0; t < 9; ++t) {
      const int dy = t / 3 - 1, dx = t % 3 - 1;
      short8 bh2[2], bl2[2];
      #pragma unroll
      for (int j = 0; j < 2; ++j) {
        int s = ((wv + dy + 1) * 34 + xsl[j] + dx + 1) * CP + quad * 8;
        bh2[j] = *(const short8*)&sh[s];
        bl2[j] = *(const short8*)&sl[s];
      }
      const unsigned short* wrh = wh + (size_t)t * OC * IC + (size_t)l15 * IC + quad * 8 + k0;
      const unsigned short* wrl = wl + (size_t)t * OC * IC + (size_t)l15 * IC + quad * 8 + k0;
      #pragma unroll
      for (int m = 0; m < OM; ++m) {
        short8 ah = *(const short8*)(wrh + (size_t)m * 16 * IC);
        short8 al = *(const short8*)(wrl + (size_t)m * 16 * IC);
        #pragma unroll
        for (int j = 0; j < 2; ++j) {
          acc[m][j] = __builtin_amdgcn_mfma_f32_16x16x32_bf16(ah, bh2[j], acc[m][j], 0, 0, 0);
          acc[m][j] = __builtin_amdgcn_mfma_f32_16x16x32_bf16(ah, bl2[j], acc[m][j], 0, 0, 0);
          acc[m][j] = __builtin_amdgcn_mfma_f32_16x16x32_bf16(al, bh2[j], acc[m][j], 0, 0, 0);
        }
      }
    }
    __syncthreads();
  }

  #pragma unroll
  for (int m = 0; m < OM; ++m) {
    const int oc0 = m * 16 + quad * 4;
    #pragma unroll
    for (int j = 0; j < 2; ++j) {
      size_t o = (size_t)b * out_ss
               + ((size_t)(y + 1) * 66 + (xbase + xsl[j] + 1)) * OC + oc0;
      ushort4 h4, l4;
      unsigned short hh, ll;
      float v;
      v = acc[m][j][0]; if (RELU) v = fmaxf(v, 0.f); split2(v, hh, ll); h4.x = hh; l4.x = ll;
      v = acc[m][j][1]; if (RELU) v = fmaxf(v, 0.f); split2(v, hh, ll); h4.y = hh; l4.y = ll;
      v = acc[m][j][2]; if (RELU) v = fmaxf(v, 0.f); split2(v, hh, ll); h4.z = hh; l4.z = ll;
      v = acc[m][j][3]; if (RELU) v = fmaxf(v, 0.f); split2(v, hh, ll); h4.w = hh; l4.w = ll;
      *(ushort4*)(outh + o) = h4;
      *(ushort4*)(outl + o) = l4;
    }
  }
}

// ======== bf16 3x3, LDS-staged, CP=40, 2 x-tiles, 16 waves/CU (decoder) ====
template<int IC, int OC, bool HAS_BIAS, bool RELU>
__global__ void __launch_bounds__(256, 4) mfma_dec3(
    const unsigned short* __restrict__ in, const unsigned short* __restrict__ wt,
    const float* __restrict__ bias, unsigned short* __restrict__ out)
{
  constexpr int OM = OC / 16;
  constexpr int CP = 40;
  __shared__ unsigned short sp[6 * 34 * CP];
  const int in_ss  = 4356 * IC;
  const int out_ss = 4356 * OC;
  const int tid = threadIdx.x;
  const int wv = tid >> 6, lane = tid & 63;
  const int quad = lane >> 4, l15 = lane & 15;

  const int id = blockIdx.x;
  const int xcd = id & 7;
  const int slot = id >> 3;
  const int bi = slot >> 5;
  const int r = slot & 31;
  const int xb = r >> 4;
  const int yb = r & 15;
  const int b = bi * 8 + xcd;
  const int y0 = yb * 4;
  const int y = y0 + wv;
  const int xbase = xb * 32;

  int xsl[2];
  #pragma unroll
  for (int j = 0; j < 2; ++j) xsl[j] = j * 16 + l15;
  const unsigned short* inb = in + (size_t)b * in_ss;

  f32x4 acc[OM][2];
  #pragma unroll
  for (int m = 0; m < OM; ++m) {
    const int oc0 = m * 16 + quad * 4;
    f32x4 ini = {0.f, 0.f, 0.f, 0.f};
    if (HAS_BIAS) {
      float4 bs = *(const float4*)(bias + oc0);
      ini[0] = bs.x; ini[1] = bs.y; ini[2] = bs.z; ini[3] = bs.w;
    }
    #pragma unroll
    for (int j = 0; j < 2; ++j) acc[m][j] = ini;
  }

  for (int k0 = 0; k0 < IC; k0 += 32) {
    for (int idx = tid; idx < 816; idx += 256) {
      int row = idx / 136;
      int rem = idx - row * 136;
      int col = rem >> 2;
      int v = (rem & 3) << 3;
      size_t g = ((size_t)(y0 + row) * 66 + xbase + col) * IC + k0 + v;
      *(ushort8*)&sp[(row * 34 + col) * CP + v] = *(const ushort8*)(inb + g);
    }
    __syncthreads();

    #pragma unroll
    for (int t = 0; t < 9; ++t) {
      const int dy = t / 3 - 1, dx = t % 3 - 1;
      short8 fb[2];
      #pragma unroll
      for (int j = 0; j < 2; ++j) {
        int s = ((wv + dy + 1) * 34 + xsl[j] + dx + 1) * CP + quad * 8;
        fb[j] = *(const short8*)&sp[s];
      }
      const unsigned short* wr = wt + (size_t)t * OC * IC + (size_t)l15 * IC + quad * 8 + k0;
      #pragma unroll
      for (int m = 0; m < OM; ++m) {
        short8 fa = *(const short8*)(wr + (size_t)m * 16 * IC);
        #pragma unroll
        for (int j = 0; j < 2; ++j)
          acc[m][j] = __builtin_amdgcn_mfma_f32_16x16x32_bf16(fa, fb[j], acc[m][j], 0, 0, 0);
      }
    }
    __syncthreads();
  }

  #pragma unroll
  for (int m = 0; m < OM; ++m) {
    const int oc0 = m * 16 + quad * 4;
    #pragma unroll
    for (int j = 0; j < 2; ++j) {
      unsigned short* o = out + (size_t)b * out_ss
                        + ((size_t)(y + 1) * 66 + (xbase + xsl[j] + 1)) * OC + oc0;
      ushort4 u4;
      float v;
      v = acc[m][j][0]; if (RELU) v = fmaxf(v, 0.f); u4.x = f2bf(v);
      v = acc[m][j][1]; if (RELU) v = fmaxf(v, 0.f); u4.y = f2bf(v);
      v = acc[m][j][2]; if (RELU) v = fmaxf(v, 0.f); u4.z = f2bf(v);
      v = acc[m][j][3]; if (RELU) v = fmaxf(v, 0.f); u4.w = f2bf(v);
      *(ushort4*)o = u4;
    }
  }
}

// ======== bf16x3 MFMA 1x1+skip (encoder, unchanged r16) ====================
template<int IC, int OC, bool RELU>
__global__ void __launch_bounds__(256) mfma_enc1x1(
    const unsigned short* __restrict__ inh, const unsigned short* __restrict__ inl,
    const unsigned short* __restrict__ wh, const unsigned short* __restrict__ wl,
    const unsigned short* __restrict__ skh, const unsigned short* __restrict__ skl,
    unsigned short* __restrict__ outh, unsigned short* __restrict__ outl)
{
  constexpr int OM = OC / 16;
  const int in_ss  = 4356 * IC;
  const int out_ss = 4356 * OC;
  const int tid = threadIdx.x;
  const int wv = tid >> 6, lane = tid & 63;
  const int quad = lane >> 4, l15 = lane & 15;

  const int id = blockIdx.x;
  const int xcd = id & 7;
  const int slot = id >> 3;
  const int bi = slot >> 4;
  const int yb = slot & 15;
  const int b = bi * 8 + xcd;
  const int y = yb * 4 + wv;

  int xs[4];
  #pragma unroll
  for (int j = 0; j < 4; ++j) xs[j] = j * 16 + l15;
  const unsigned short* ibh = inh + (size_t)b * in_ss;
  const unsigned short* ibl = inl + (size_t)b * in_ss;

  f32x4 acc[OM][4];
  #pragma unroll
  for (int m = 0; m < OM; ++m) {
    const int oc0 = m * 16 + quad * 4;
    #pragma unroll
    for (int j = 0; j < 4; ++j) {
      f32x4 a;
      size_t s = (size_t)b * out_ss + ((size_t)(y + 1) * 66 + (xs[j] + 1)) * OC + oc0;
      ushort4 sh = *(const ushort4*)(skh + s);
      ushort4 sl = *(const ushort4*)(skl + s);
      a[0] = bf2f(sh.x) + bf2f(sl.x);
      a[1] = bf2f(sh.y) + bf2f(sl.y);
      a[2] = bf2f(sh.z) + bf2f(sl.z);
      a[3] = bf2f(sh.w) + bf2f(sl.w);
      acc[m][j] = a;
    }
  }

  const unsigned short* wrh = wh + (size_t)l15 * IC + quad * 8;
  const unsigned short* wrl = wl + (size_t)l15 * IC + quad * 8;
  #pragma unroll
  for (int k0 = 0; k0 < IC; k0 += 32) {
    short8 bh[4], bl[4];
    #pragma unroll
    for (int j = 0; j < 4; ++j) {
      int off = ((y + 1) * 66 + (xs[j] + 1)) * IC;
      bh[j] = *(const short8*)(ibh + off + quad * 8 + k0);
      bl[j] = *(const short8*)(ibl + off + quad * 8 + k0);
    }
    #pragma unroll
    for (int m = 0; m < OM; ++m) {
      short8 ah = *(const short8*)(wrh + (size_t)m * 16 * IC + k0);
      short8 al = *(const short8*)(wrl + (size_t)m * 16 * IC + k0);
      #pragma unroll
      for (int j = 0; j < 4; ++j) {
        acc[m][j] = __builtin_amdgcn_mfma_f32_16x16x32_bf16(ah, bh[j], acc[m][j], 0, 0, 0);
        acc[m][j] = __builtin_amdgcn_mfma_f32_16x16x32_bf16(ah, bl[j], acc[m][j], 0, 0, 0);
        acc[m][j] = __builtin_amdgcn_mfma_f32_16x16x32_bf16(al, bh[j], acc[m][j], 0, 0, 0);
      }
    }
  }

  #pragma unroll
  for (int m = 0; m < OM; ++m) {
    const int oc0 = m * 16 + quad * 4;
    #pragma unroll
    for (int j = 0; j < 4; ++j) {
      size_t o = (size_t)b * out_ss + ((size_t)(y + 1) * 66 + (xs[j] + 1)) * OC + oc0;
      ushort4 h4, l4;
      unsigned short hh, ll;
      float v;
      v = acc[m][j][0]; if (RELU) v = fmaxf(v, 0.f); split2(v, hh, ll); h4.x = hh; l4.x = ll;
      v = acc[m][j][1]; if (RELU) v = fmaxf(v, 0.f); split2(v, hh, ll); h4.y = hh; l4.y = ll;
      v = acc[m][j][2]; if (RELU) v = fmaxf(v, 0.f); split2(v, hh, ll); h4.z = hh; l4.z = ll;
      v = acc[m][j][3]; if (RELU) v = fmaxf(v, 0.f); split2(v, hh, ll); h4.w = hh; l4.w = ll;
      *(ushort4*)(outh + o) = h4;
      *(ushort4*)(outl + o) = l4;
    }
  }
}

// ======== vq on MFMA (unchanged) ===========================================
__global__ void __launch_bounds__(256) vq_mfma(
    const unsigned short* __restrict__ xh, const unsigned short* __restrict__ xl,
    const unsigned short* __restrict__ wvh, const unsigned short* __restrict__ wvl,
    const unsigned short* __restrict__ evh, const unsigned short* __restrict__ evl,
    const float* __restrict__ emb, const float* __restrict__ e2,
    const float* __restrict__ vb,
    float* __restrict__ qn, unsigned short* __restrict__ dqb,
    float* __restrict__ sum_sq, int* __restrict__ hist)
{
  __shared__ float zsh[4][16][65];
  __shared__ int lh[64];
  const int tid = threadIdx.x;
  const int wv = tid >> 6, lane = tid & 63;
  const int quad = lane >> 4, l15 = lane & 15;
  const int y = blockIdx.x;
  const int b = blockIdx.z;
  const int x = wv * 16 + l15;
  if (tid < 64) lh[tid] = 0;

  f32x4 zacc[4];
  #pragma unroll
  for (int m = 0; m < 4; ++m) {
    float4 bv = *(const float4*)(vb + m * 16 + quad * 4);
    zacc[m][0] = bv.x; zacc[m][1] = bv.y; zacc[m][2] = bv.z; zacc[m][3] = bv.w;
  }
  size_t xoff = ((size_t)b * 4356 + (size_t)(y + 1) * 66 + (x + 1)) * 128;
  #pragma unroll
  for (int k0 = 0; k0 < 128; k0 += 32) {
    short8 bh = *(const short8*)(xh + xoff + k0 + quad * 8);
    short8 bl = *(const short8*)(xl + xoff + k0 + quad * 8);
    #pragma unroll
    for (int m = 0; m < 4; ++m) {
      short8 ah = *(const short8*)(wvh + (size_t)(m * 16 + l15) * 128 + k0 + quad * 8);
      short8 al = *(const short8*)(wvl + (size_t)(m * 16 + l15) * 128 + k0 + quad * 8);
      zacc[m] = __builtin_amdgcn_mfma_f32_16x16x32_bf16(ah, bh, zacc[m], 0, 0, 0);
      zacc[m] = __builtin_amdgcn_mfma_f32_16x16x32_bf16(ah, bl, zacc[m], 0, 0, 0);
      zacc[m] = __builtin_amdgcn_mfma_f32_16x16x32_bf16(al, bh, zacc[m], 0, 0, 0);
    }
  }

  float z2p = 0.f;
  #pragma unroll
  for (int m = 0; m < 4; ++m)
    #pragma unroll
    for (int r = 0; r < 4; ++r) {
      float zv = zacc[m][r];
      zsh[wv][l15][m * 16 + quad * 4 + r] = zv;
      z2p += zv * zv;
    }
  z2p += __shfl_xor(z2p, 16);
  z2p += __shfl_xor(z2p, 32);
  __syncthreads();

  f32x4 dacc[4];
  #pragma unroll
  for (int m = 0; m < 4; ++m) { dacc[m][0]=0.f; dacc[m][1]=0.f; dacc[m][2]=0.f; dacc[m][3]=0.f; }
  #pragma unroll
  for (int k0 = 0; k0 < 64; k0 += 32) {
    short8 bh, bl;
    #pragma unroll
    for (int j = 0; j < 8; ++j) {
      float zv = zsh[wv][l15][k0 + quad * 8 + j];
      unsigned short hh, ll;
      split2(zv, hh, ll);
      bh[j] = (short)hh; bl[j] = (short)ll;
    }
    #pragma unroll
    for (int m = 0; m < 4; ++m) {
      short8 ah = *(const short8*)(evh + (size_t)(m * 16 + l15) * 64 + k0 + quad * 8);
      short8 al = *(const short8*)(evl + (size_t)(m * 16 + l15) * 64 + k0 + quad * 8);
      dacc[m] = __builtin_amdgcn_mfma_f32_16x16x32_bf16(ah, bh, dacc[m], 0, 0, 0);
      dacc[m] = __builtin_amdgcn_mfma_f32_16x16x32_bf16(ah, bl, dacc[m], 0, 0, 0);
      dacc[m] = __builtin_amdgcn_mfma_f32_16x16x32_bf16(al, bh, dacc[m], 0, 0, 0);
    }
  }

  float best = INFINITY;
  int bidx = 64;
  #pragma unroll
  for (int m = 0; m < 4; ++m) {
    float4 e2v = *(const float4*)(e2 + m * 16 + quad * 4);
    #pragma unroll
    for (int r = 0; r < 4; ++r) {
      float e2s = (r == 0) ? e2v.x : (r == 1) ? e2v.y : (r == 2) ? e2v.z : e2v.w;
      float d = z2p + e2s - 2.f * dacc[m][r];
      int code = m * 16 + quad * 4 + r;
      if (d < best || (d == best && code < bidx)) { best = d; bidx = code; }
    }
  }
  {
    float ob = __shfl_xor(best, 16);
    int   oi = __shfl_xor(bidx, 16);
    if (ob < best || (ob == best && oi < bidx)) { best = ob; bidx = oi; }
    ob = __shfl_xor(best, 32);
    oi = __shfl_xor(bidx, 32);
    if (ob < best || (ob == best && oi < bidx)) { best = ob; bidx = oi; }
  }

  float ev[16];
  #pragma unroll
  for (int i = 0; i < 4; ++i) {
    float4 t = *(const float4*)(emb + (size_t)bidx * 64 + quad * 16 + i * 4);
    ev[i * 4] = t.x; ev[i * 4 + 1] = t.y; ev[i * 4 + 2] = t.z; ev[i * 4 + 3] = t.w;
  }
  float sq = 0.f;
  #pragma unroll
  for (int i = 0; i < 16; ++i) {
    float zv = zsh[wv][l15][quad * 16 + i];
    float df = ev[i] - zv;
    sq += df * df;
  }
  #pragma unroll
  for (int off = 1; off < 64; off <<= 1) sq += __shfl_xor(sq, off);
  if (lane == 0) atomicAdd(sum_sq, sq);
  if (quad == 0) atomicAdd(&lh[bidx], 1);

  int pos = y * 64 + x;
  float* qb = qn + (size_t)b * 262144 + (size_t)(quad * 16) * 4096 + pos;
  #pragma unroll
  for (int i = 0; i < 16; ++i) qb[(size_t)i * 4096] = ev[i];

  unsigned short* dq = dqb + ((size_t)b * 4356 + (size_t)(y + 1) * 66 + (x + 1)) * 64 + quad * 16;
  ushort8 d0, d1;
  #pragma unroll
  for (int i = 0; i < 8; ++i) { d0[i] = f2bf(ev[i]); d1[i] = f2bf(ev[i + 8]); }
  *(ushort8*)dq = d0;
  *(ushort8*)(dq + 8) = d1;

  __syncthreads();
  if (tid < 64) atomicAdd(&hist[tid], lh[tid]);
}

// ======== bf16 MFMA tap-GEMM (decoder MODE 1/2, unchanged r16) =============
template<int IC, int OC, int MODE, bool HAS_BIAS, bool HAS_SKIP, bool RELU>
__global__ void __launch_bounds__(256) mfma_conv(
    const unsigned short* __restrict__ in, const unsigned short* __restrict__ wt,
    const float* __restrict__ bias, const unsigned short* __restrict__ skip,
    unsigned short* __restrict__ out, int in_ss, int out_ss)
{
  constexpr int OM = OC / 16;
  constexpr int NT = (MODE == 1) ? 4 : 1;
  constexpr int NP = (MODE == 1) ? 4 : 1;
  constexpr int PERB = 16 * NP;
  const int tid = threadIdx.x;
  const int wv = tid >> 6, lane = tid & 63;
  const int quad = lane >> 4, l15 = lane & 15;

  const int id = blockIdx.x;
  const int xcd = id & 7;
  const int slot = id >> 3;
  const int bi = slot / PERB;
  int r2 = slot - bi * PERB;
  int p = 0;
  if (MODE == 1) { p = r2 >> 4; r2 &= 15; }
  const int yb = r2;
  const int b = bi * 8 + xcd;
  const int y = yb * 4 + wv;

  int ry = 0, rx = 0;
  if (MODE == 1) {
    ry = p >> 1; rx = p & 1;
    wt  += (size_t)p * 4 * OC * IC;
    out += (size_t)p * 4356 * OC;
  }
  int xs[4];
  #pragma unroll
  for (int j = 0; j < 4; ++j) xs[j] = j * 16 + l15;
  const unsigned short* inb = in + (size_t)b * (size_t)in_ss;

  f32x4 acc[OM][4];
  #pragma unroll
  for (int m = 0; m < OM; ++m) {
    const int oc0 = m * 16 + quad * 4;
    f32x4 ini = {0.f, 0.f, 0.f, 0.f};
    if (HAS_BIAS) {
      float4 bs = *(const float4*)(bias + oc0);
      ini[0] = bs.x; ini[1] = bs.y; ini[2] = bs.z; ini[3] = bs.w;
    }
    #pragma unroll
    for (int j = 0; j < 4; ++j) {
      f32x4 a = ini;
      if (HAS_SKIP) {
        size_t s = (size_t)b * (size_t)out_ss + ((size_t)(y + 1) * 66 + (xs[j] + 1)) * OC + oc0;
        ushort4 sv = *(const ushort4*)(skip + s);
        a[0] += bf2f(sv.x); a[1] += bf2f(sv.y); a[2] += bf2f(sv.z); a[3] += bf2f(sv.w);
      }
      acc[m][j] = a;
    }
  }

  #pragma unroll
  for (int t = 0; t < NT; ++t) {
    const int dy = (MODE == 1) ? (ry - (t >> 1)) : 0;
    const int dx = (MODE == 1) ? (rx - (t & 1)) : 0;
    const unsigned short* wr = wt + (size_t)t * OC * IC + (size_t)l15 * IC + quad * 8;
    #pragma unroll
    for (int k0 = 0; k0 < IC; k0 += 32) {
      short8 fb[4];
      #pragma unroll
      for (int j = 0; j < 4; ++j)
        fb[j] = *(const short8*)(inb + ((size_t)(y + dy + 1) * 66 + (xs[j] + dx + 1)) * IC + quad * 8 + k0);
      #pragma unroll
      for (int m = 0; m < OM; ++m) {
        short8 fa = *(const short8*)(wr + (size_t)m * 16 * IC + k0);
        #pragma unroll
        for (int j = 0; j < 4; ++j)
          acc[m][j] = __builtin_amdgcn_mfma_f32_16x16x32_bf16(fa, fb[j], acc[m][j], 0, 0, 0);
      }
    }
  }

  #pragma unroll
  for (int m = 0; m < OM; ++m) {
    const int oc0 = m * 16 + quad * 4;
    #pragma unroll
    for (int j = 0; j < 4; ++j) {
      unsigned short* o = out + (size_t)b * (size_t)out_ss
                        + ((size_t)(y + 1) * 66 + (xs[j] + 1)) * OC + oc0;
      ushort4 u4;
      float v;
      v = acc[m][j][0]; if (RELU) v = fmaxf(v, 0.f); u4.x = f2bf(v);
      v = acc[m][j][1]; if (RELU) v = fmaxf(v, 0.f); u4.y = f2bf(v);
      v = acc[m][j][2]; if (RELU) v = fmaxf(v, 0.f); u4.z = f2bf(v);
      v = acc[m][j][3]; if (RELU) v = fmaxf(v, 0.f); u4.w = f2bf(v);
      *(ushort4*)o = u4;
    }
  }
}

// ======== dec_c3: LDS-free, short8 channel-octet loads (unchanged) =========
__global__ void __launch_bounds__(256) dec3_t(
    const unsigned short* __restrict__ p4, const float* __restrict__ w,
    const float* __restrict__ bias, float* __restrict__ out)
{
  int tid = threadIdx.x;
  int yr = tid >> 7, x = tid & 127;
  int y  = blockIdx.x * 2 + yr;
  int b  = blockIdx.z;

  const int kt[2][2] = {{1, 3}, {0, 2}};
  const int dt[2][2] = {{1, 0}, {2, 1}};

  const unsigned short* base[9];
  #pragma unroll
  for (int dy = 0; dy < 3; ++dy) {
    int iy = y + dy - 1;
    int py = iy & 1, u = iy >> 1;
    #pragma unroll
    for (int dx = 0; dx < 3; ++dx) {
      int ix = x + dx - 1;
      int px = ix & 1, v = ix >> 1;
      base[dy * 3 + dx] = p4 + ((size_t)(b * 4 + py * 2 + px) * 4356
                                + (size_t)(u + 1) * 66 + (v + 1)) * 64;
    }
  }

  float acc[4] = {0.f, 0.f, 0.f, 0.f};
  for (int oct = 0; oct < 8; ++oct) {
    ushort8 s[9];
    #pragma unroll
    for (int t = 0; t < 9; ++t)
      s[t] = *(const ushort8*)(base[t] + oct * 8);

    #pragma unroll
    for (int j = 0; j < 8; ++j) {
      const float* wp = w + (size_t)(oct * 8 + j) * 16;
      float v9[9];
      #pragma unroll
      for (int t = 0; t < 9; ++t) v9[t] = bf2f(s[t][j]);
      #pragma unroll
      for (int ry = 0; ry < 2; ++ry)
        #pragma unroll
        for (int rx = 0; rx < 2; ++rx)
          #pragma unroll
          for (int a = 0; a < 2; ++a)
            #pragma unroll
            for (int c2 = 0; c2 < 2; ++c2)
              acc[ry * 2 + rx] += v9[dt[ry][a] * 3 + dt[rx][c2]]
                                * wp[kt[ry][a] * 4 + kt[rx][c2]];
    }
  }

  float b0 = bias[0];
  float* ob = out + (size_t)b * 65536;
  #pragma unroll
  for (int ry = 0; ry < 2; ++ry)
    #pragma unroll
    for (int rx = 0; rx < 2; ++rx)
      ob[(2 * y + ry) * 256 + 2 * x + rx] = tanhf(acc[ry * 2 + rx] + b0);
}

// ======== aux: multi-buffer pad-ring zero ==================================
struct RingArgs {
  unsigned short* p[5];
  int icl[5];
  int H[5];
  int planes[5];
};
__global__ void rings_k(RingArgs a)
{
  int bi = blockIdx.y;
  if ((int)blockIdx.x >= a.planes[bi]) return;
  int H = a.H[bi];
  int icl = a.icl[bi];
  int C = 1 << icl;
  unsigned short* pl = a.p[bi] + (size_t)blockIdx.x * H * H * C;
  int cells = 4 * H - 4;
  int total = cells * C;
  for (int idx = threadIdx.x; idx < total; idx += 256) {
    int cell = idx >> icl;
    int e = idx & (C - 1);
    int row, col;
    if (cell < H)             { row = 0;     col = cell; }
    else if (cell < 2 * H)    { row = H - 1; col = cell - H; }
    else if (cell < 2 * H + (H - 2)) { row = cell - 2 * H + 1; col = 0; }
    else                      { row = cell - 2 * H - (H - 2) + 1; col = H - 1; }
    pl[((size_t)row * H + col) * C + e] = 0;
  }
}

// ======== aux: repack decoder weights (unchanged) ==========================
__global__ void repack_k(const float* __restrict__ c1w, const float* __restrict__ r1w,
                         const float* __restrict__ r2w, const float* __restrict__ c2w,
                         unsigned short* __restrict__ W)
{
  int idx = blockIdx.x * 256 + threadIdx.x;
  if (idx >= 286720) return;
  float val;
  if (idx < 73728) {
    int t = idx / 8192, rem = idx & 8191;
    int oc = rem >> 6, ic = rem & 63;
    int ky = t / 3, kx = t - ky * 3;
    val = c1w[((ic * 128 + oc) * 3 + (2 - ky)) * 3 + (2 - kx)];
  } else if (idx < 147456) {
    int j = idx - 73728;
    int t = j / 8192, rem = j & 8191;
    int oc = rem >> 7, ic = rem & 127;
    int ky = t / 3, kx = t - ky * 3;
    val = r1w[((oc * 128 + ic) * 3 + ky) * 3 + kx];
  } else if (idx < 155648) {
    int j = idx - 147456;
    int oc = j >> 6, ic = j & 63;
    val = r2w[oc * 64 + ic];
  } else {
    int j = idx - 155648;
    int p = j >> 15;
    int t2 = (j >> 13) & 3;
    int oc = (j >> 7) & 63;
    int ic = j & 127;
    int ry = p >> 1, rx = p & 1;
    int aY = t2 >> 1, aX = t2 & 1;
    int ky = aY ? (3 - ry) : (1 - ry);
    int kx = aX ? (3 - rx) : (1 - rx);
    val = c2w[((ic * 64 + oc) * 4 + ky) * 4 + kx];
  }
  W[idx] = f2bf(val);
}

// ======== aux: repack encoder weights hi/lo (unchanged) ====================
__global__ void repack_enc_k(const float* __restrict__ c2w, const float* __restrict__ c3w,
                             const float* __restrict__ r1w, const float* __restrict__ r2w,
                             unsigned short* __restrict__ Wh, unsigned short* __restrict__ Wl)
{
  int idx = blockIdx.x * 256 + threadIdx.x;
  if (idx >= 360448) return;
  float val;
  if (idx < 131072) {
    int t = idx >> 13;
    int rem = idx & 8191;
    int oc = rem >> 6, ic = rem & 63;
    val = c2w[(((size_t)oc * 64 + ic) << 4) + t];
  } else if (idx < 278528) {
    int j = idx - 131072;
    int t = j / 16384;
    int rem = j & 16383;
    int oc = rem >> 7, ic = rem & 127;
    val = c3w[((size_t)oc * 128 + ic) * 9 + t];
  } else if (idx < 352256) {
    int j = idx - 278528;
    int t = j / 8192;
    int rem = j & 8191;
    int oc = rem >> 7, ic = rem & 127;
    val = r1w[((size_t)oc * 128 + ic) * 9 + t];
  } else {
    int j = idx - 352256;
    int oc = j >> 6, ic = j & 63;
    val = r2w[oc * 64 + ic];
  }
  unsigned short h = f2bf(val);
  Wh[idx] = h;
  Wl[idx] = f2bf(val - bf2f(h));
}

// ======== aux: repack vq weights hi/lo + e2 table (unchanged) ==============
__global__ void repack_vq_k(const float* __restrict__ vqw, const float* __restrict__ emb,
                            unsigned short* __restrict__ wvh, unsigned short* __restrict__ wvl,
                            unsigned short* __restrict__ evh, unsigned short* __restrict__ evl,
                            float* __restrict__ e2)
{
  int idx = blockIdx.x * 256 + threadIdx.x;
  if (idx < 8192) {
    float v = vqw[idx];
    unsigned short h = f2bf(v);
    wvh[idx] = h;
    wvl[idx] = f2bf(v - bf2f(h));
  } else if (idx < 12288) {
    int j = idx - 8192;
    float v = emb[j];
    unsigned short h = f2bf(v);
    evh[j] = h;
    evl[j] = f2bf(v - bf2f(h));
  }
  if (idx < 64) {
    float s = 0.f;
    for (int d = 0; d < 64; ++d) { float e = emb[idx * 64 + d]; s += e * e; }
    e2[idx] = s;
  }
}

// ======== scratch init + scalar finalize ===================================
__global__ void init_k(float* sum_sq, int* hist)
{
  int t = threadIdx.x;
  if (t == 0) sum_sq[0] = 0.f;
  if (t < 64) hist[t] = 0;
}

__global__ void finalize_k(const float* __restrict__ sum_sq, const int* __restrict__ hist,
                           float* __restrict__ loss_out, float* __restrict__ perp_out)
{
  if (threadIdx.x == 0) {
    float mse = sum_sq[0] / (float)NELEM;
    loss_out[0] = 1.25f * mse;
    float ent = 0.f;
    for (int k = 0; k < 64; ++k) {
      float p = (float)hist[k] / (float)NPOS;
      ent += p * logf(p + 1e-10f);
    }
    perp_out[0] = expf(-ent);
  }
}

// ---------------------------------------------------------------------------
extern "C" void kernel_launch(void* const* d_in, const int* in_sizes, int n_in,
                              void* d_out, int out_size, void* d_ws, size_t ws_size,
                              hipStream_t stream)
{
  const float* x        = (const float*)d_in[0];
  const float* enc_c1_w = (const float*)d_in[1];
  const float* enc_c1_b = (const float*)d_in[2];
  const float* enc_c2_w = (const float*)d_in[3];
  const float* enc_c2_b = (const float*)d_in[4];
  const float* enc_c3_w = (const float*)d_in[5];
  const float* enc_c3_b = (const float*)d_in[6];
  const float* enc_r1_w = (const float*)d_in[7];
  const float* enc_r2_w = (const float*)d_in[8];
  const float* vqc_w    = (const float*)d_in[9];
  const float* vqc_b    = (const float*)d_in[10];
  const float* emb      = (const float*)d_in[11];
  const float* dec_c1_w = (const float*)d_in[12];
  const float* dec_c1_b = (const float*)d_in[13];
  const float* dec_r1_w = (const float*)d_in[14];
  const float* dec_r2_w = (const float*)d_in[15];
  const float* dec_c2_w = (const float*)d_in[16];
  const float* dec_c2_b = (const float*)d_in[17];
  const float* dec_c3_w = (const float*)d_in[18];
  const float* dec_c3_b = (const float*)d_in[19];

  float* out      = (float*)d_out;
  float* loss_out = out;
  float* xre_out  = out + 1;
  float* perp_out = out + 1 + 2097152;
  float* qn_out   = out + 2 + 2097152;

  float* sum_sq = (float*)d_ws;
  int*   hist   = (int*)d_ws + 1;
  char*  pool   = (char*)d_ws + 1024;

  unsigned short* Wd   = (unsigned short*)(pool + 0);
  unsigned short* Weh  = (unsigned short*)(pool + 600000);
  unsigned short* Wel  = (unsigned short*)(pool + 1400000);
  unsigned short* Wvh  = (unsigned short*)(pool + 2121728);
  unsigned short* Wvl  = (unsigned short*)(pool + 2138112);
  unsigned short* Evh  = (unsigned short*)(pool + 2154496);
  unsigned short* Evl  = (unsigned short*)(pool + 2162688);
  float*          E2   = (float*)(pool + 2170880);
  unsigned short* E1ph = (unsigned short*)(pool + 2200000);
  unsigned short* E1pl = (unsigned short*)(pool + 73600000);
  unsigned short* B2h  = (unsigned short*)(pool + 145000000);
  unsigned short* B2l  = (unsigned short*)(pool + 181000000);
  unsigned short* R0h  = (unsigned short*)(pool + 2200000);
  unsigned short* R0l  = (unsigned short*)(pool + 38000000);
  unsigned short* Hh   = (unsigned short*)(pool + 74000000);
  unsigned short* Hl   = (unsigned short*)(pool + 92000000);
  unsigned short* S    = (unsigned short*)(pool + 110000000);
  unsigned short* X1h  = (unsigned short*)(pool + 145000000);
  unsigned short* X1l  = (unsigned short*)(pool + 181000000);
  unsigned short* X2h  = (unsigned short*)(pool + 2200000);
  unsigned short* X2l  = (unsigned short*)(pool + 38000000);
  unsigned short* Dq   = (unsigned short*)(pool + 217000000);
  unsigned short* Y1   = (unsigned short*)(pool + 145000000);
  unsigned short* Y2   = (unsigned short*)(pool + 181000000);
  unsigned short* P4   = (unsigned short*)(pool + 2200000);

  const int SS64  = 278784;
  const int SS128 = 557568;
  const int SSP4  = 1115136;

  hipLaunchKernelGGL(init_k, dim3(1), dim3(128), 0, stream, sum_sq, hist);
  hipLaunchKernelGGL(repack_k, dim3(1120), dim3(256), 0, stream,
                     dec_c1_w, dec_r1_w, dec_r2_w, dec_c2_w, Wd);
  hipLaunchKernelGGL(repack_enc_k, dim3(1408), dim3(256), 0, stream,
                     enc_c2_w, enc_c3_w, enc_r1_w, enc_r2_w, Weh, Wel);
  hipLaunchKernelGGL(repack_vq_k, dim3(48), dim3(256), 0, stream,
                     vqc_w, emb, Wvh, Wvl, Evh, Evl, E2);

  // rings group 1: E1 parity planes + B2 + Dq
  {
    RingArgs a;
    a.p[0] = E1ph; a.icl[0] = 6; a.H[0] = 66; a.planes[0] = 128;
    a.p[1] = E1pl; a.icl[1] = 6; a.H[1] = 66; a.planes[1] = 128;
    a.p[2] = B2h;  a.icl[2] = 7; a.H[2] = 66; a.planes[2] = 32;
    a.p[3] = B2l;  a.icl[3] = 7; a.H[3] = 66; a.planes[3] = 32;
    a.p[4] = Dq;   a.icl[4] = 6; a.H[4] = 66; a.planes[4] = 32;
    hipLaunchKernelGGL(rings_k, dim3(128, 5), dim3(256), 0, stream, a);
  }

  // ---- encoder ----
  hipLaunchKernelGGL(enc1_t, dim3(64, 4, 32), dim3(256), 0, stream,
                     x, enc_c1_w, enc_c1_b, E1ph, E1pl);
  hipLaunchKernelGGL(mfma_enc2p, dim3(512), dim3(256), 0, stream,
                     E1ph, E1pl, Weh, Wel, enc_c2_b, B2h, B2l);

  // rings group 2
  {
    RingArgs a;
    a.p[0] = R0h; a.icl[0] = 7; a.H[0] = 66; a.planes[0] = 32;
    a.p[1] = R0l; a.icl[1] = 7; a.H[1] = 66; a.planes[1] = 32;
    a.p[2] = Hh;  a.icl[2] = 6; a.H[2] = 66; a.planes[2] = 32;
    a.p[3] = Hl;  a.icl[3] = 6; a.H[3] = 66; a.planes[3] = 32;
    a.p[4] = S;   a.icl[4] = 6; a.H[4] = 66; a.planes[4] = 32;
    hipLaunchKernelGGL(rings_k, dim3(32, 5), dim3(256), 0, stream, a);
  }

  hipLaunchKernelGGL((mfma_enc3<128, 128, true, true>),
                     dim3(1024), dim3(256), 0, stream,
                     B2h, B2l, Weh + 131072, Wel + 131072, enc_c3_b, R0h, R0l);

  // rings group 3
  {
    RingArgs a;
    a.p[0] = X1h; a.icl[0] = 7; a.H[0] = 66; a.planes[0] = 32;
    a.p[1] = X1l; a.icl[1] = 7; a.H[1] = 66; a.planes[1] = 32;
    a.p[2] = nullptr; a.icl[2] = 0; a.H[2] = 2; a.planes[2] = 0;
    a.p[3] = nullptr; a.icl[3] = 0; a.H[3] = 2; a.planes[3] = 0;
    a.p[4] = nullptr; a.icl[4] = 0; a.H[4] = 2; a.planes[4] = 0;
    hipLaunchKernelGGL(rings_k, dim3(32, 2), dim3(256), 0, stream, a);
  }

  hipLaunchKernelGGL((mfma_enc3<128, 64, false, true>),
                     dim3(1024), dim3(256), 0, stream,
                     R0h, R0l, Weh + 278528, Wel + 278528, nullptr, Hh, Hl);
  hipLaunchKernelGGL((mfma_enc1x1<64, 128, true>),
                     dim3(512), dim3(256), 0, stream,
                     Hh, Hl, Weh + 352256, Wel + 352256, R0h, R0l, X1h, X1l);

  // rings group 4
  {
    RingArgs a;
    a.p[0] = X2h; a.icl[0] = 7; a.H[0] = 66; a.planes[0] = 32;
    a.p[1] = X2l; a.icl[1] = 7; a.H[1] = 66; a.planes[1] = 32;
    a.p[2] = nullptr; a.icl[2] = 0; a.H[2] = 2; a.planes[2] = 0;
    a.p[3] = nullptr; a.icl[3] = 0; a.H[3] = 2; a.planes[3] = 0;
    a.p[4] = nullptr; a.icl[4] = 0; a.H[4] = 2; a.planes[4] = 0;
    hipLaunchKernelGGL(rings_k, dim3(32, 2), dim3(256), 0, stream, a);
  }

  hipLaunchKernelGGL((mfma_enc3<128, 64, false, true>),
                     dim3(1024), dim3(256), 0, stream,
                     X1h, X1l, Weh + 278528, Wel + 278528, nullptr, Hh, Hl);
  hipLaunchKernelGGL((mfma_enc1x1<64, 128, true>),
                     dim3(512), dim3(256), 0, stream,
                     Hh, Hl, Weh + 352256, Wel + 352256, X1h, X1l, X2h, X2l);

  // ---- VQ on MFMA ----
  hipLaunchKernelGGL(vq_mfma, dim3(64, 1, 32), dim3(256), 0, stream,
                     X2h, X2l, Wvh, Wvl, Evh, Evl, emb, E2, vqc_b,
                     qn_out, Dq, sum_sq, hist);

  // rings group 5: decoder regions
  {
    RingArgs a;
    a.p[0] = Y1;  a.icl[0] = 7; a.H[0] = 66; a.planes[0] = 32;
    a.p[1] = Y2;  a.icl[1] = 7; a.H[1] = 66; a.planes[1] = 32;
    a.p[2] = P4;  a.icl[2] = 6; a.H[2] = 66; a.planes[2] = 128;
    a.p[3] = nullptr; a.icl[3] = 0; a.H[3] = 2; a.planes[3] = 0;
    a.p[4] = nullptr; a.icl[4] = 0; a.H[4] = 2; a.planes[4] = 0;
    hipLaunchKernelGGL(rings_k, dim3(128, 3), dim3(256), 0, stream, a);
  }

  // ---- decoder (bf16 MFMA; 3x3 via 2-tile LDS-staged kernel) ----
  hipLaunchKernelGGL((mfma_dec3<64, 128, true, true>),
                     dim3(1024), dim3(256), 0, stream,
                     Dq, Wd, dec_c1_b, Y1);
  hipLaunchKernelGGL((mfma_dec3<128, 64, false, true>),
                     dim3(1024), dim3(256), 0, stream,
                     Y1, Wd + 73728, nullptr, S);
  hipLaunchKernelGGL((mfma_conv<64, 128, 2, false, true, true>),
                     dim3(512), dim3(256), 0, stream,
                     S, Wd + 147456, nullptr, Y1, Y2, SS64, SS128);
  hipLaunchKernelGGL((mfma_dec3<128, 64, false, true>),
                     dim3(1024), dim3(256), 0, stream,
                     Y2, Wd + 73728, nullptr, S);
  hipLaunchKernelGGL((mfma_conv<64, 128, 2, false, true, true>),
                     dim3(512), dim3(256), 0, stream,
                     S, Wd + 147456, nullptr, Y2, Y1, SS64, SS128);

  // dec_c2: 4 parities folded into the swizzled grid
  hipLaunchKernelGGL((mfma_conv<128, 64, 1, true, false, true>),
                     dim3(2048), dim3(256), 0, stream,
                     Y1, Wd + 155648, dec_c2_b, nullptr, P4, SS128, SSP4);

  hipLaunchKernelGGL(dec3_t, dim3(64, 1, 32), dim3(256), 0, stream,
                     P4, dec_c3_w, dec_c3_b, xre_out);

  hipLaunchKernelGGL(finalize_k, dim3(1), dim3(64), 0, stream,
                     sum_sq, hist, loss_out, perp_out);
}

// Round 19
// 1654.503 us; speedup vs baseline: 1.1551x; 1.1551x over previous
//
#include <hip/hip_runtime.h>
#include <cmath>

// ---------------------------------------------------------------------------
// VQ-VAE forward, round 19 = exact revert to r16 (1663us, session best).
// r17 (register prefetch pipelining): neutral -- barrier drain structural.
// r18 (occupancy via half tiles): -13% -- load-instruction count doubled,
// per-wave MFMA:load ratio halved; occupancy cannot compensate (r11 lesson).
// The enc3 ~237us plateau is structural to the 2-barrier K-loop (guide §5);
// r16 is the measured optimum of this design space.
// ---------------------------------------------------------------------------

static constexpr int NPOS  = 131072;
static constexpr long long NELEM = 8388608;

typedef __attribute__((ext_vector_type(8))) short short8;
typedef __attribute__((ext_vector_type(8))) unsigned short ushort8;
typedef __attribute__((ext_vector_type(4))) float f32x4;

__device__ __forceinline__ unsigned short f2bf(float f) {
  unsigned int x = __float_as_uint(f);
  unsigned int r = (x + 0x7fffu + ((x >> 16) & 1u)) >> 16;
  return (unsigned short)r;
}
__device__ __forceinline__ float bf2f(unsigned short u) {
  return __uint_as_float(((unsigned int)u) << 16);
}
__device__ __forceinline__ void split2(float v, unsigned short& h, unsigned short& l) {
  unsigned short hh = f2bf(v);
  h = hh;
  l = f2bf(v - bf2f(hh));
}

// ======== enc_c1: 4x4 s2 p1 -> hi/lo in 4 PARITY planes (66x66x64 pad) =====
__global__ void __launch_bounds__(256) enc1_t(
    const float* __restrict__ in, const float* __restrict__ w,
    const float* __restrict__ bias,
    unsigned short* __restrict__ outh, unsigned short* __restrict__ outl)
{
  int tid = threadIdx.x;
  int wv = tid >> 6, lane = tid & 63;
  int rr = wv >> 1, px = wv & 1;
  int oy  = blockIdx.x * 2 + rr;
  int ox  = 2 * lane + px;
  int oc0 = blockIdx.y * 16;
  int b   = blockIdx.z;

  const float* pl = in + (size_t)b * 65536;
  float v[16];
  #pragma unroll
  for (int ky = 0; ky < 4; ++ky) {
    int iy = 2 * oy - 1 + ky;
    #pragma unroll
    for (int kx = 0; kx < 4; ++kx) {
      int ix = 2 * ox - 1 + kx;
      v[ky * 4 + kx] = (iy >= 0 && iy < 256 && ix >= 0 && ix < 256)
                       ? pl[iy * 256 + ix] : 0.f;
    }
  }
  float acc[16];
  #pragma unroll
  for (int o = 0; o < 16; ++o) acc[o] = bias[oc0 + o];
  #pragma unroll
  for (int t = 0; t < 16; ++t)
    #pragma unroll
    for (int o = 0; o < 16; ++o)
      acc[o] += v[t] * w[(size_t)(oc0 + o) * 16 + t];

  int pp = ((oy & 1) << 1) | px;
  int u = oy >> 1, vv = lane;
  size_t o = ((size_t)(b * 4 + pp)) * 278784
           + ((size_t)(u + 1) * 66 + (vv + 1)) * 64 + oc0;
  ushort8 h0, h1, l0, l1;
  #pragma unroll
  for (int k = 0; k < 8; ++k) {
    unsigned short hh, ll;
    split2(fmaxf(acc[k], 0.f), hh, ll);      h0[k] = hh; l0[k] = ll;
    split2(fmaxf(acc[k + 8], 0.f), hh, ll);  h1[k] = hh; l1[k] = ll;
  }
  *(ushort8*)(outh + o)     = h0;
  *(ushort8*)(outh + o + 8) = h1;
  *(ushort8*)(outl + o)     = l0;
  *(ushort8*)(outl + o + 8) = l1;
}

// ======== enc_c2 as 4 parity 2x2 convs, LDS-staged, CP=40 ==================
__global__ void __launch_bounds__(256) mfma_enc2p(
    const unsigned short* __restrict__ inh, const unsigned short* __restrict__ inl,
    const unsigned short* __restrict__ wh, const unsigned short* __restrict__ wl,
    const float* __restrict__ bias,
    unsigned short* __restrict__ outh, unsigned short* __restrict__ outl)
{
  constexpr int IC = 64, OC = 128, OM = 8, CP = 40;
  __shared__ unsigned short sh[6 * 66 * CP];
  __shared__ unsigned short sl[6 * 66 * CP];
  const int out_ss = 4356 * OC;
  const int tid = threadIdx.x;
  const int wv = tid >> 6, lane = tid & 63;
  const int quad = lane >> 4, l15 = lane & 15;

  const int id = blockIdx.x;
  const int xcd = id & 7;
  const int slot = id >> 3;
  const int bi = slot >> 4;
  const int yb = slot & 15;
  const int b = bi * 8 + xcd;
  const int y0 = yb * 4;
  const int y = y0 + wv;

  int xs[4];
  #pragma unroll
  for (int j = 0; j < 4; ++j) xs[j] = j * 16 + l15;

  f32x4 acc[OM][4];
  #pragma unroll
  for (int m = 0; m < OM; ++m) {
    const int oc0 = m * 16 + quad * 4;
    float4 bs = *(const float4*)(bias + oc0);
    f32x4 ini;
    ini[0] = bs.x; ini[1] = bs.y; ini[2] = bs.z; ini[3] = bs.w;
    #pragma unroll
    for (int j = 0; j < 4; ++j) acc[m][j] = ini;
  }

  for (int k0 = 0; k0 < IC; k0 += 32) {
    #pragma unroll 1
    for (int pp = 0; pp < 4; ++pp) {
      const int py = pp >> 1, px = pp & 1;
      const unsigned short* pbh = inh + (size_t)(b * 4 + pp) * 278784;
      const unsigned short* pbl = inl + (size_t)(b * 4 + pp) * 278784;
      for (int idx = tid; idx < 1584; idx += 256) {
        int row = idx / 264;
        int rem = idx - row * 264;
        int col = rem >> 2;
        int v = (rem & 3) << 3;
        size_t g = ((size_t)(y0 + row) * 66 + col) * IC + k0 + v;
        int s = (row * 66 + col) * CP + v;
        *(ushort8*)&sh[s] = *(const ushort8*)(pbh + g);
        *(ushort8*)&sl[s] = *(const ushort8*)(pbl + g);
      }
      __syncthreads();

      #pragma unroll
      for (int a = 0; a < 2; ++a) {
        const int ky = py ? (2 * a) : (1 + 2 * a);
        const int du = py ? (a - 1) : a;
        #pragma unroll
        for (int c2 = 0; c2 < 2; ++c2) {
          const int kx = px ? (2 * c2) : (1 + 2 * c2);
          const int dv = px ? (c2 - 1) : c2;
          const int t = ky * 4 + kx;
          short8 bh4[4], bl4[4];
          #pragma unroll
          for (int j = 0; j < 4; ++j) {
            int s = ((wv + du + 1) * 66 + xs[j] + dv + 1) * CP + quad * 8;
            bh4[j] = *(const short8*)&sh[s];
            bl4[j] = *(const short8*)&sl[s];
          }
          const unsigned short* wrh = wh + (size_t)t * OC * IC + (size_t)l15 * IC + quad * 8 + k0;
          const unsigned short* wrl = wl + (size_t)t * OC * IC + (size_t)l15 * IC + quad * 8 + k0;
          #pragma unroll
          for (int m = 0; m < OM; ++m) {
            short8 ah = *(const short8*)(wrh + (size_t)m * 16 * IC);
            short8 al = *(const short8*)(wrl + (size_t)m * 16 * IC);
            #pragma unroll
            for (int j = 0; j < 4; ++j) {
              acc[m][j] = __builtin_amdgcn_mfma_f32_16x16x32_bf16(ah, bh4[j], acc[m][j], 0, 0, 0);
              acc[m][j] = __builtin_amdgcn_mfma_f32_16x16x32_bf16(ah, bl4[j], acc[m][j], 0, 0, 0);
              acc[m][j] = __builtin_amdgcn_mfma_f32_16x16x32_bf16(al, bh4[j], acc[m][j], 0, 0, 0);
            }
          }
        }
      }
      __syncthreads();
    }
  }

  #pragma unroll
  for (int m = 0; m < OM; ++m) {
    const int oc0 = m * 16 + quad * 4;
    #pragma unroll
    for (int j = 0; j < 4; ++j) {
      size_t o = (size_t)b * out_ss + ((size_t)(y + 1) * 66 + (xs[j] + 1)) * OC + oc0;
      ushort4 h4, l4;
      unsigned short hh, ll;
      float v;
      v = fmaxf(acc[m][j][0], 0.f); split2(v, hh, ll); h4.x = hh; l4.x = ll;
      v = fmaxf(acc[m][j][1], 0.f); split2(v, hh, ll); h4.y = hh; l4.y = ll;
      v = fmaxf(acc[m][j][2], 0.f); split2(v, hh, ll); h4.z = hh; l4.z = ll;
      v = fmaxf(acc[m][j][3], 0.f); split2(v, hh, ll); h4.w = hh; l4.w = ll;
      *(ushort4*)(outh + o) = h4;
      *(ushort4*)(outl + o) = l4;
    }
  }
}

// ======== bf16x3 3x3 MFMA conv, LDS-staged, CP=40 (encoder) ================
template<int IC, int OC, bool BIAS, bool RELU>
__global__ void __launch_bounds__(256) mfma_enc3(
    const unsigned short* __restrict__ inh, const unsigned short* __restrict__ inl,
    const unsigned short* __restrict__ wh, const unsigned short* __restrict__ wl,
    const float* __restrict__ bias,
    unsigned short* __restrict__ outh, unsigned short* __restrict__ outl)
{
  constexpr int OM = OC / 16;
  constexpr int CP = 40;
  __shared__ unsigned short sh[6 * 66 * CP];
  __shared__ unsigned short sl[6 * 66 * CP];
  const int in_ss  = 4356 * IC;
  const int out_ss = 4356 * OC;
  const int tid = threadIdx.x;
  const int wv = tid >> 6, lane = tid & 63;
  const int quad = lane >> 4, l15 = lane & 15;

  const int id = blockIdx.x;
  const int xcd = id & 7;
  const int slot = id >> 3;
  const int bi = slot >> 4;
  const int yb = slot & 15;
  const int b = bi * 8 + xcd;
  const int y0 = yb * 4;
  const int y = y0 + wv;

  int xs[4];
  #pragma unroll
  for (int j = 0; j < 4; ++j) xs[j] = j * 16 + l15;
  const unsigned short* ibh = inh + (size_t)b * in_ss;
  const unsigned short* ibl = inl + (size_t)b * in_ss;

  f32x4 acc[OM][4];
  #pragma unroll
  for (int m = 0; m < OM; ++m) {
    const int oc0 = m * 16 + quad * 4;
    f32x4 ini = {0.f, 0.f, 0.f, 0.f};
    if (BIAS) {
      float4 bs = *(const float4*)(bias + oc0);
      ini[0] = bs.x; ini[1] = bs.y; ini[2] = bs.z; ini[3] = bs.w;
    }
    #pragma unroll
    for (int j = 0; j < 4; ++j) acc[m][j] = ini;
  }

  for (int k0 = 0; k0 < IC; k0 += 32) {
    for (int idx = tid; idx < 1584; idx += 256) {
      int row = idx / 264;
      int rem = idx - row * 264;
      int col = rem >> 2;
      int v = (rem & 3) << 3;
      size_t g = ((size_t)(y0 + row) * 66 + col) * IC + k0 + v;
      int s = (row * 66 + col) * CP + v;
      *(ushort8*)&sh[s] = *(const ushort8*)(ibh + g);
      *(ushort8*)&sl[s] = *(const ushort8*)(ibl + g);
    }
    __syncthreads();

    #pragma unroll
    for (int t = 0; t < 9; ++t) {
      const int dy = t / 3 - 1, dx = t % 3 - 1;
      short8 bh4[4], bl4[4];
      #pragma unroll
      for (int j = 0; j < 4; ++j) {
        int s = ((wv + dy + 1) * 66 + xs[j] + dx + 1) * CP + quad * 8;
        bh4[j] = *(const short8*)&sh[s];
        bl4[j] = *(const short8*)&sl[s];
      }
      const unsigned short* wrh = wh + (size_t)t * OC * IC + (size_t)l15 * IC + quad * 8 + k0;
      const unsigned short* wrl = wl + (size_t)t * OC * IC + (size_t)l15 * IC + quad * 8 + k0;
      #pragma unroll
      for (int m = 0; m < OM; ++m) {
        short8 ah = *(const short8*)(wrh + (size_t)m * 16 * IC);
        short8 al = *(const short8*)(wrl + (size_t)m * 16 * IC);
        #pragma unroll
        for (int j = 0; j < 4; ++j) {
          acc[m][j] = __builtin_amdgcn_mfma_f32_16x16x32_bf16(ah, bh4[j], acc[m][j], 0, 0, 0);
          acc[m][j] = __builtin_amdgcn_mfma_f32_16x16x32_bf16(ah, bl4[j], acc[m][j], 0, 0, 0);
          acc[m][j] = __builtin_amdgcn_mfma_f32_16x16x32_bf16(al, bh4[j], acc[m][j], 0, 0, 0);
        }
      }
    }
    __syncthreads();
  }

  #pragma unroll
  for (int m = 0; m < OM; ++m) {
    const int oc0 = m * 16 + quad * 4;
    #pragma unroll
    for (int j = 0; j < 4; ++j) {
      size_t o = (size_t)b * out_ss + ((size_t)(y + 1) * 66 + (xs[j] + 1)) * OC + oc0;
      ushort4 h4, l4;
      unsigned short hh, ll;
      float v;
      v = acc[m][j][0]; if (RELU) v = fmaxf(v, 0.f); split2(v, hh, ll); h4.x = hh; l4.x = ll;
      v = acc[m][j][1]; if (RELU) v = fmaxf(v, 0.f); split2(v, hh, ll); h4.y = hh; l4.y = ll;
      v = acc[m][j][2]; if (RELU) v = fmaxf(v, 0.f); split2(v, hh, ll); h4.z = hh; l4.z = ll;
      v = acc[m][j][3]; if (RELU) v = fmaxf(v, 0.f); split2(v, hh, ll); h4.w = hh; l4.w = ll;
      *(ushort4*)(outh + o) = h4;
      *(ushort4*)(outl + o) = l4;
    }
  }
}

// ======== bf16 3x3 MFMA conv, LDS-staged, CP=40 (decoder) ==================
template<int IC, int OC, bool HAS_BIAS, bool RELU>
__global__ void __launch_bounds__(256) mfma_dec3(
    const unsigned short* __restrict__ in, const unsigned short* __restrict__ wt,
    const float* __restrict__ bias, unsigned short* __restrict__ out)
{
  constexpr int OM = OC / 16;
  constexpr int CP = 40;
  __shared__ unsigned short sp[6 * 66 * CP];
  const int in_ss  = 4356 * IC;
  const int out_ss = 4356 * OC;
  const int tid = threadIdx.x;
  const int wv = tid >> 6, lane = tid & 63;
  const int quad = lane >> 4, l15 = lane & 15;

  const int id = blockIdx.x;
  const int xcd = id & 7;
  const int slot = id >> 3;
  const int bi = slot >> 4;
  const int yb = slot & 15;
  const int b = bi * 8 + xcd;
  const int y0 = yb * 4;
  const int y = y0 + wv;

  int xs[4];
  #pragma unroll
  for (int j = 0; j < 4; ++j) xs[j] = j * 16 + l15;
  const unsigned short* inb = in + (size_t)b * in_ss;

  f32x4 acc[OM][4];
  #pragma unroll
  for (int m = 0; m < OM; ++m) {
    const int oc0 = m * 16 + quad * 4;
    f32x4 ini = {0.f, 0.f, 0.f, 0.f};
    if (HAS_BIAS) {
      float4 bs = *(const float4*)(bias + oc0);
      ini[0] = bs.x; ini[1] = bs.y; ini[2] = bs.z; ini[3] = bs.w;
    }
    #pragma unroll
    for (int j = 0; j < 4; ++j) acc[m][j] = ini;
  }

  for (int k0 = 0; k0 < IC; k0 += 32) {
    for (int idx = tid; idx < 1584; idx += 256) {
      int row = idx / 264;
      int rem = idx - row * 264;
      int col = rem >> 2;
      int v = (rem & 3) << 3;
      size_t g = ((size_t)(y0 + row) * 66 + col) * IC + k0 + v;
      *(ushort8*)&sp[(row * 66 + col) * CP + v] = *(const ushort8*)(inb + g);
    }
    __syncthreads();

    #pragma unroll
    for (int t = 0; t < 9; ++t) {
      const int dy = t / 3 - 1, dx = t % 3 - 1;
      short8 fb[4];
      #pragma unroll
      for (int j = 0; j < 4; ++j) {
        int s = ((wv + dy + 1) * 66 + xs[j] + dx + 1) * CP + quad * 8;
        fb[j] = *(const short8*)&sp[s];
      }
      const unsigned short* wr = wt + (size_t)t * OC * IC + (size_t)l15 * IC + quad * 8 + k0;
      #pragma unroll
      for (int m = 0; m < OM; ++m) {
        short8 fa = *(const short8*)(wr + (size_t)m * 16 * IC);
        #pragma unroll
        for (int j = 0; j < 4; ++j)
          acc[m][j] = __builtin_amdgcn_mfma_f32_16x16x32_bf16(fa, fb[j], acc[m][j], 0, 0, 0);
      }
    }
    __syncthreads();
  }

  #pragma unroll
  for (int m = 0; m < OM; ++m) {
    const int oc0 = m * 16 + quad * 4;
    #pragma unroll
    for (int j = 0; j < 4; ++j) {
      unsigned short* o = out + (size_t)b * out_ss
                        + ((size_t)(y + 1) * 66 + (xs[j] + 1)) * OC + oc0;
      ushort4 u4;
      float v;
      v = acc[m][j][0]; if (RELU) v = fmaxf(v, 0.f); u4.x = f2bf(v);
      v = acc[m][j][1]; if (RELU) v = fmaxf(v, 0.f); u4.y = f2bf(v);
      v = acc[m][j][2]; if (RELU) v = fmaxf(v, 0.f); u4.z = f2bf(v);
      v = acc[m][j][3]; if (RELU) v = fmaxf(v, 0.f); u4.w = f2bf(v);
      *(ushort4*)o = u4;
    }
  }
}

// ======== bf16x3 MFMA 1x1+skip (encoder) ===================================
template<int IC, int OC, bool RELU>
__global__ void __launch_bounds__(256) mfma_enc1x1(
    const unsigned short* __restrict__ inh, const unsigned short* __restrict__ inl,
    const unsigned short* __restrict__ wh, const unsigned short* __restrict__ wl,
    const unsigned short* __restrict__ skh, const unsigned short* __restrict__ skl,
    unsigned short* __restrict__ outh, unsigned short* __restrict__ outl)
{
  constexpr int OM = OC / 16;
  const int in_ss  = 4356 * IC;
  const int out_ss = 4356 * OC;
  const int tid = threadIdx.x;
  const int wv = tid >> 6, lane = tid & 63;
  const int quad = lane >> 4, l15 = lane & 15;

  const int id = blockIdx.x;
  const int xcd = id & 7;
  const int slot = id >> 3;
  const int bi = slot >> 4;
  const int yb = slot & 15;
  const int b = bi * 8 + xcd;
  const int y = yb * 4 + wv;

  int xs[4];
  #pragma unroll
  for (int j = 0; j < 4; ++j) xs[j] = j * 16 + l15;
  const unsigned short* ibh = inh + (size_t)b * in_ss;
  const unsigned short* ibl = inl + (size_t)b * in_ss;

  f32x4 acc[OM][4];
  #pragma unroll
  for (int m = 0; m < OM; ++m) {
    const int oc0 = m * 16 + quad * 4;
    #pragma unroll
    for (int j = 0; j < 4; ++j) {
      f32x4 a;
      size_t s = (size_t)b * out_ss + ((size_t)(y + 1) * 66 + (xs[j] + 1)) * OC + oc0;
      ushort4 sh = *(const ushort4*)(skh + s);
      ushort4 sl = *(const ushort4*)(skl + s);
      a[0] = bf2f(sh.x) + bf2f(sl.x);
      a[1] = bf2f(sh.y) + bf2f(sl.y);
      a[2] = bf2f(sh.z) + bf2f(sl.z);
      a[3] = bf2f(sh.w) + bf2f(sl.w);
      acc[m][j] = a;
    }
  }

  const unsigned short* wrh = wh + (size_t)l15 * IC + quad * 8;
  const unsigned short* wrl = wl + (size_t)l15 * IC + quad * 8;
  #pragma unroll
  for (int k0 = 0; k0 < IC; k0 += 32) {
    short8 bh[4], bl[4];
    #pragma unroll
    for (int j = 0; j < 4; ++j) {
      int off = ((y + 1) * 66 + (xs[j] + 1)) * IC;
      bh[j] = *(const short8*)(ibh + off + quad * 8 + k0);
      bl[j] = *(const short8*)(ibl + off + quad * 8 + k0);
    }
    #pragma unroll
    for (int m = 0; m < OM; ++m) {
      short8 ah = *(const short8*)(wrh + (size_t)m * 16 * IC + k0);
      short8 al = *(const short8*)(wrl + (size_t)m * 16 * IC + k0);
      #pragma unroll
      for (int j = 0; j < 4; ++j) {
        acc[m][j] = __builtin_amdgcn_mfma_f32_16x16x32_bf16(ah, bh[j], acc[m][j], 0, 0, 0);
        acc[m][j] = __builtin_amdgcn_mfma_f32_16x16x32_bf16(ah, bl[j], acc[m][j], 0, 0, 0);
        acc[m][j] = __builtin_amdgcn_mfma_f32_16x16x32_bf16(al, bh[j], acc[m][j], 0, 0, 0);
      }
    }
  }

  #pragma unroll
  for (int m = 0; m < OM; ++m) {
    const int oc0 = m * 16 + quad * 4;
    #pragma unroll
    for (int j = 0; j < 4; ++j) {
      size_t o = (size_t)b * out_ss + ((size_t)(y + 1) * 66 + (xs[j] + 1)) * OC + oc0;
      ushort4 h4, l4;
      unsigned short hh, ll;
      float v;
      v = acc[m][j][0]; if (RELU) v = fmaxf(v, 0.f); split2(v, hh, ll); h4.x = hh; l4.x = ll;
      v = acc[m][j][1]; if (RELU) v = fmaxf(v, 0.f); split2(v, hh, ll); h4.y = hh; l4.y = ll;
      v = acc[m][j][2]; if (RELU) v = fmaxf(v, 0.f); split2(v, hh, ll); h4.z = hh; l4.z = ll;
      v = acc[m][j][3]; if (RELU) v = fmaxf(v, 0.f); split2(v, hh, ll); h4.w = hh; l4.w = ll;
      *(ushort4*)(outh + o) = h4;
      *(ushort4*)(outl + o) = l4;
    }
  }
}

// ======== vq on MFMA ========================================================
__global__ void __launch_bounds__(256) vq_mfma(
    const unsigned short* __restrict__ xh, const unsigned short* __restrict__ xl,
    const unsigned short* __restrict__ wvh, const unsigned short* __restrict__ wvl,
    const unsigned short* __restrict__ evh, const unsigned short* __restrict__ evl,
    const float* __restrict__ emb, const float* __restrict__ e2,
    const float* __restrict__ vb,
    float* __restrict__ qn, unsigned short* __restrict__ dqb,
    float* __restrict__ sum_sq, int* __restrict__ hist)
{
  __shared__ float zsh[4][16][65];
  __shared__ int lh[64];
  const int tid = threadIdx.x;
  const int wv = tid >> 6, lane = tid & 63;
  const int quad = lane >> 4, l15 = lane & 15;
  const int y = blockIdx.x;
  const int b = blockIdx.z;
  const int x = wv * 16 + l15;
  if (tid < 64) lh[tid] = 0;

  f32x4 zacc[4];
  #pragma unroll
  for (int m = 0; m < 4; ++m) {
    float4 bv = *(const float4*)(vb + m * 16 + quad * 4);
    zacc[m][0] = bv.x; zacc[m][1] = bv.y; zacc[m][2] = bv.z; zacc[m][3] = bv.w;
  }
  size_t xoff = ((size_t)b * 4356 + (size_t)(y + 1) * 66 + (x + 1)) * 128;
  #pragma unroll
  for (int k0 = 0; k0 < 128; k0 += 32) {
    short8 bh = *(const short8*)(xh + xoff + k0 + quad * 8);
    short8 bl = *(const short8*)(xl + xoff + k0 + quad * 8);
    #pragma unroll
    for (int m = 0; m < 4; ++m) {
      short8 ah = *(const short8*)(wvh + (size_t)(m * 16 + l15) * 128 + k0 + quad * 8);
      short8 al = *(const short8*)(wvl + (size_t)(m * 16 + l15) * 128 + k0 + quad * 8);
      zacc[m] = __builtin_amdgcn_mfma_f32_16x16x32_bf16(ah, bh, zacc[m], 0, 0, 0);
      zacc[m] = __builtin_amdgcn_mfma_f32_16x16x32_bf16(ah, bl, zacc[m], 0, 0, 0);
      zacc[m] = __builtin_amdgcn_mfma_f32_16x16x32_bf16(al, bh, zacc[m], 0, 0, 0);
    }
  }

  float z2p = 0.f;
  #pragma unroll
  for (int m = 0; m < 4; ++m)
    #pragma unroll
    for (int r = 0; r < 4; ++r) {
      float zv = zacc[m][r];
      zsh[wv][l15][m * 16 + quad * 4 + r] = zv;
      z2p += zv * zv;
    }
  z2p += __shfl_xor(z2p, 16);
  z2p += __shfl_xor(z2p, 32);
  __syncthreads();

  f32x4 dacc[4];
  #pragma unroll
  for (int m = 0; m < 4; ++m) { dacc[m][0]=0.f; dacc[m][1]=0.f; dacc[m][2]=0.f; dacc[m][3]=0.f; }
  #pragma unroll
  for (int k0 = 0; k0 < 64; k0 += 32) {
    short8 bh, bl;
    #pragma unroll
    for (int j = 0; j < 8; ++j) {
      float zv = zsh[wv][l15][k0 + quad * 8 + j];
      unsigned short hh, ll;
      split2(zv, hh, ll);
      bh[j] = (short)hh; bl[j] = (short)ll;
    }
    #pragma unroll
    for (int m = 0; m < 4; ++m) {
      short8 ah = *(const short8*)(evh + (size_t)(m * 16 + l15) * 64 + k0 + quad * 8);
      short8 al = *(const short8*)(evl + (size_t)(m * 16 + l15) * 64 + k0 + quad * 8);
      dacc[m] = __builtin_amdgcn_mfma_f32_16x16x32_bf16(ah, bh, dacc[m], 0, 0, 0);
      dacc[m] = __builtin_amdgcn_mfma_f32_16x16x32_bf16(ah, bl, dacc[m], 0, 0, 0);
      dacc[m] = __builtin_amdgcn_mfma_f32_16x16x32_bf16(al, bh, dacc[m], 0, 0, 0);
    }
  }

  float best = INFINITY;
  int bidx = 64;
  #pragma unroll
  for (int m = 0; m < 4; ++m) {
    float4 e2v = *(const float4*)(e2 + m * 16 + quad * 4);
    #pragma unroll
    for (int r = 0; r < 4; ++r) {
      float e2s = (r == 0) ? e2v.x : (r == 1) ? e2v.y : (r == 2) ? e2v.z : e2v.w;
      float d = z2p + e2s - 2.f * dacc[m][r];
      int code = m * 16 + quad * 4 + r;
      if (d < best || (d == best && code < bidx)) { best = d; bidx = code; }
    }
  }
  {
    float ob = __shfl_xor(best, 16);
    int   oi = __shfl_xor(bidx, 16);
    if (ob < best || (ob == best && oi < bidx)) { best = ob; bidx = oi; }
    ob = __shfl_xor(best, 32);
    oi = __shfl_xor(bidx, 32);
    if (ob < best || (ob == best && oi < bidx)) { best = ob; bidx = oi; }
  }

  float ev[16];
  #pragma unroll
  for (int i = 0; i < 4; ++i) {
    float4 t = *(const float4*)(emb + (size_t)bidx * 64 + quad * 16 + i * 4);
    ev[i * 4] = t.x; ev[i * 4 + 1] = t.y; ev[i * 4 + 2] = t.z; ev[i * 4 + 3] = t.w;
  }
  float sq = 0.f;
  #pragma unroll
  for (int i = 0; i < 16; ++i) {
    float zv = zsh[wv][l15][quad * 16 + i];
    float df = ev[i] - zv;
    sq += df * df;
  }
  #pragma unroll
  for (int off = 1; off < 64; off <<= 1) sq += __shfl_xor(sq, off);
  if (lane == 0) atomicAdd(sum_sq, sq);
  if (quad == 0) atomicAdd(&lh[bidx], 1);

  int pos = y * 64 + x;
  float* qb = qn + (size_t)b * 262144 + (size_t)(quad * 16) * 4096 + pos;
  #pragma unroll
  for (int i = 0; i < 16; ++i) qb[(size_t)i * 4096] = ev[i];

  unsigned short* dq = dqb + ((size_t)b * 4356 + (size_t)(y + 1) * 66 + (x + 1)) * 64 + quad * 16;
  ushort8 d0, d1;
  #pragma unroll
  for (int i = 0; i < 8; ++i) { d0[i] = f2bf(ev[i]); d1[i] = f2bf(ev[i + 8]); }
  *(ushort8*)dq = d0;
  *(ushort8*)(dq + 8) = d1;

  __syncthreads();
  if (tid < 64) atomicAdd(&hist[tid], lh[tid]);
}

// ======== bf16 MFMA tap-GEMM (decoder MODE 1/2) ============================
template<int IC, int OC, int MODE, bool HAS_BIAS, bool HAS_SKIP, bool RELU>
__global__ void __launch_bounds__(256) mfma_conv(
    const unsigned short* __restrict__ in, const unsigned short* __restrict__ wt,
    const float* __restrict__ bias, const unsigned short* __restrict__ skip,
    unsigned short* __restrict__ out, int in_ss, int out_ss)
{
  constexpr int OM = OC / 16;
  constexpr int NT = (MODE == 1) ? 4 : 1;
  constexpr int NP = (MODE == 1) ? 4 : 1;
  constexpr int PERB = 16 * NP;
  const int tid = threadIdx.x;
  const int wv = tid >> 6, lane = tid & 63;
  const int quad = lane >> 4, l15 = lane & 15;

  const int id = blockIdx.x;
  const int xcd = id & 7;
  const int slot = id >> 3;
  const int bi = slot / PERB;
  int r2 = slot - bi * PERB;
  int p = 0;
  if (MODE == 1) { p = r2 >> 4; r2 &= 15; }
  const int yb = r2;
  const int b = bi * 8 + xcd;
  const int y = yb * 4 + wv;

  int ry = 0, rx = 0;
  if (MODE == 1) {
    ry = p >> 1; rx = p & 1;
    wt  += (size_t)p * 4 * OC * IC;
    out += (size_t)p * 4356 * OC;
  }
  int xs[4];
  #pragma unroll
  for (int j = 0; j < 4; ++j) xs[j] = j * 16 + l15;
  const unsigned short* inb = in + (size_t)b * (size_t)in_ss;

  f32x4 acc[OM][4];
  #pragma unroll
  for (int m = 0; m < OM; ++m) {
    const int oc0 = m * 16 + quad * 4;
    f32x4 ini = {0.f, 0.f, 0.f, 0.f};
    if (HAS_BIAS) {
      float4 bs = *(const float4*)(bias + oc0);
      ini[0] = bs.x; ini[1] = bs.y; ini[2] = bs.z; ini[3] = bs.w;
    }
    #pragma unroll
    for (int j = 0; j < 4; ++j) {
      f32x4 a = ini;
      if (HAS_SKIP) {
        size_t s = (size_t)b * (size_t)out_ss + ((size_t)(y + 1) * 66 + (xs[j] + 1)) * OC + oc0;
        ushort4 sv = *(const ushort4*)(skip + s);
        a[0] += bf2f(sv.x); a[1] += bf2f(sv.y); a[2] += bf2f(sv.z); a[3] += bf2f(sv.w);
      }
      acc[m][j] = a;
    }
  }

  #pragma unroll
  for (int t = 0; t < NT; ++t) {
    const int dy = (MODE == 1) ? (ry - (t >> 1)) : 0;
    const int dx = (MODE == 1) ? (rx - (t & 1)) : 0;
    const unsigned short* wr = wt + (size_t)t * OC * IC + (size_t)l15 * IC + quad * 8;
    #pragma unroll
    for (int k0 = 0; k0 < IC; k0 += 32) {
      short8 fb[4];
      #pragma unroll
      for (int j = 0; j < 4; ++j)
        fb[j] = *(const short8*)(inb + ((size_t)(y + dy + 1) * 66 + (xs[j] + dx + 1)) * IC + quad * 8 + k0);
      #pragma unroll
      for (int m = 0; m < OM; ++m) {
        short8 fa = *(const short8*)(wr + (size_t)m * 16 * IC + k0);
        #pragma unroll
        for (int j = 0; j < 4; ++j)
          acc[m][j] = __builtin_amdgcn_mfma_f32_16x16x32_bf16(fa, fb[j], acc[m][j], 0, 0, 0);
      }
    }
  }

  #pragma unroll
  for (int m = 0; m < OM; ++m) {
    const int oc0 = m * 16 + quad * 4;
    #pragma unroll
    for (int j = 0; j < 4; ++j) {
      unsigned short* o = out + (size_t)b * (size_t)out_ss
                        + ((size_t)(y + 1) * 66 + (xs[j] + 1)) * OC + oc0;
      ushort4 u4;
      float v;
      v = acc[m][j][0]; if (RELU) v = fmaxf(v, 0.f); u4.x = f2bf(v);
      v = acc[m][j][1]; if (RELU) v = fmaxf(v, 0.f); u4.y = f2bf(v);
      v = acc[m][j][2]; if (RELU) v = fmaxf(v, 0.f); u4.z = f2bf(v);
      v = acc[m][j][3]; if (RELU) v = fmaxf(v, 0.f); u4.w = f2bf(v);
      *(ushort4*)o = u4;
    }
  }
}

// ======== dec_c3: LDS-free, short8 channel-octet loads =====================
__global__ void __launch_bounds__(256) dec3_t(
    const unsigned short* __restrict__ p4, const float* __restrict__ w,
    const float* __restrict__ bias, float* __restrict__ out)
{
  int tid = threadIdx.x;
  int yr = tid >> 7, x = tid & 127;
  int y  = blockIdx.x * 2 + yr;
  int b  = blockIdx.z;

  const int kt[2][2] = {{1, 3}, {0, 2}};
  const int dt[2][2] = {{1, 0}, {2, 1}};

  const unsigned short* base[9];
  #pragma unroll
  for (int dy = 0; dy < 3; ++dy) {
    int iy = y + dy - 1;
    int py = iy & 1, u = iy >> 1;
    #pragma unroll
    for (int dx = 0; dx < 3; ++dx) {
      int ix = x + dx - 1;
      int px = ix & 1, v = ix >> 1;
      base[dy * 3 + dx] = p4 + ((size_t)(b * 4 + py * 2 + px) * 4356
                                + (size_t)(u + 1) * 66 + (v + 1)) * 64;
    }
  }

  float acc[4] = {0.f, 0.f, 0.f, 0.f};
  for (int oct = 0; oct < 8; ++oct) {
    ushort8 s[9];
    #pragma unroll
    for (int t = 0; t < 9; ++t)
      s[t] = *(const ushort8*)(base[t] + oct * 8);

    #pragma unroll
    for (int j = 0; j < 8; ++j) {
      const float* wp = w + (size_t)(oct * 8 + j) * 16;
      float v9[9];
      #pragma unroll
      for (int t = 0; t < 9; ++t) v9[t] = bf2f(s[t][j]);
      #pragma unroll
      for (int ry = 0; ry < 2; ++ry)
        #pragma unroll
        for (int rx = 0; rx < 2; ++rx)
          #pragma unroll
          for (int a = 0; a < 2; ++a)
            #pragma unroll
            for (int c2 = 0; c2 < 2; ++c2)
              acc[ry * 2 + rx] += v9[dt[ry][a] * 3 + dt[rx][c2]]
                                * wp[kt[ry][a] * 4 + kt[rx][c2]];
    }
  }

  float b0 = bias[0];
  float* ob = out + (size_t)b * 65536;
  #pragma unroll
  for (int ry = 0; ry < 2; ++ry)
    #pragma unroll
    for (int rx = 0; rx < 2; ++rx)
      ob[(2 * y + ry) * 256 + 2 * x + rx] = tanhf(acc[ry * 2 + rx] + b0);
}

// ======== aux: multi-buffer pad-ring zero ==================================
struct RingArgs {
  unsigned short* p[5];
  int icl[5];
  int H[5];
  int planes[5];
};
__global__ void rings_k(RingArgs a)
{
  int bi = blockIdx.y;
  if ((int)blockIdx.x >= a.planes[bi]) return;
  int H = a.H[bi];
  int icl = a.icl[bi];
  int C = 1 << icl;
  unsigned short* pl = a.p[bi] + (size_t)blockIdx.x * H * H * C;
  int cells = 4 * H - 4;
  int total = cells * C;
  for (int idx = threadIdx.x; idx < total; idx += 256) {
    int cell = idx >> icl;
    int e = idx & (C - 1);
    int row, col;
    if (cell < H)             { row = 0;     col = cell; }
    else if (cell < 2 * H)    { row = H - 1; col = cell - H; }
    else if (cell < 2 * H + (H - 2)) { row = cell - 2 * H + 1; col = 0; }
    else                      { row = cell - 2 * H - (H - 2) + 1; col = H - 1; }
    pl[((size_t)row * H + col) * C + e] = 0;
  }
}

// ======== aux: repack decoder weights ======================================
__global__ void repack_k(const float* __restrict__ c1w, const float* __restrict__ r1w,
                         const float* __restrict__ r2w, const float* __restrict__ c2w,
                         unsigned short* __restrict__ W)
{
  int idx = blockIdx.x * 256 + threadIdx.x;
  if (idx >= 286720) return;
  float val;
  if (idx < 73728) {
    int t = idx / 8192, rem = idx & 8191;
    int oc = rem >> 6, ic = rem & 63;
    int ky = t / 3, kx = t - ky * 3;
    val = c1w[((ic * 128 + oc) * 3 + (2 - ky)) * 3 + (2 - kx)];
  } else if (idx < 147456) {
    int j = idx - 73728;
    int t = j / 8192, rem = j & 8191;
    int oc = rem >> 7, ic = rem & 127;
    int ky = t / 3, kx = t - ky * 3;
    val = r1w[((oc * 128 + ic) * 3 + ky) * 3 + kx];
  } else if (idx < 155648) {
    int j = idx - 147456;
    int oc = j >> 6, ic = j & 63;
    val = r2w[oc * 64 + ic];
  } else {
    int j = idx - 155648;
    int p = j >> 15;
    int t2 = (j >> 13) & 3;
    int oc = (j >> 7) & 63;
    int ic = j & 127;
    int ry = p >> 1, rx = p & 1;
    int aY = t2 >> 1, aX = t2 & 1;
    int ky = aY ? (3 - ry) : (1 - ry);
    int kx = aX ? (3 - rx) : (1 - rx);
    val = c2w[((ic * 64 + oc) * 4 + ky) * 4 + kx];
  }
  W[idx] = f2bf(val);
}

// ======== aux: repack encoder weights hi/lo ================================
__global__ void repack_enc_k(const float* __restrict__ c2w, const float* __restrict__ c3w,
                             const float* __restrict__ r1w, const float* __restrict__ r2w,
                             unsigned short* __restrict__ Wh, unsigned short* __restrict__ Wl)
{
  int idx = blockIdx.x * 256 + threadIdx.x;
  if (idx >= 360448) return;
  float val;
  if (idx < 131072) {
    int t = idx >> 13;
    int rem = idx & 8191;
    int oc = rem >> 6, ic = rem & 63;
    val = c2w[(((size_t)oc * 64 + ic) << 4) + t];
  } else if (idx < 278528) {
    int j = idx - 131072;
    int t = j / 16384;
    int rem = j & 16383;
    int oc = rem >> 7, ic = rem & 127;
    val = c3w[((size_t)oc * 128 + ic) * 9 + t];
  } else if (idx < 352256) {
    int j = idx - 278528;
    int t = j / 8192;
    int rem = j & 8191;
    int oc = rem >> 7, ic = rem & 127;
    val = r1w[((size_t)oc * 128 + ic) * 9 + t];
  } else {
    int j = idx - 352256;
    int oc = j >> 6, ic = j & 63;
    val = r2w[oc * 64 + ic];
  }
  unsigned short h = f2bf(val);
  Wh[idx] = h;
  Wl[idx] = f2bf(val - bf2f(h));
}

// ======== aux: repack vq weights hi/lo + e2 table ==========================
__global__ void repack_vq_k(const float* __restrict__ vqw, const float* __restrict__ emb,
                            unsigned short* __restrict__ wvh, unsigned short* __restrict__ wvl,
                            unsigned short* __restrict__ evh, unsigned short* __restrict__ evl,
                            float* __restrict__ e2)
{
  int idx = blockIdx.x * 256 + threadIdx.x;
  if (idx < 8192) {
    float v = vqw[idx];
    unsigned short h = f2bf(v);
    wvh[idx] = h;
    wvl[idx] = f2bf(v - bf2f(h));
  } else if (idx < 12288) {
    int j = idx - 8192;
    float v = emb[j];
    unsigned short h = f2bf(v);
    evh[j] = h;
    evl[j] = f2bf(v - bf2f(h));
  }
  if (idx < 64) {
    float s = 0.f;
    for (int d = 0; d < 64; ++d) { float e = emb[idx * 64 + d]; s += e * e; }
    e2[idx] = s;
  }
}

// ======== scratch init + scalar finalize ===================================
__global__ void init_k(float* sum_sq, int* hist)
{
  int t = threadIdx.x;
  if (t == 0) sum_sq[0] = 0.f;
  if (t < 64) hist[t] = 0;
}

__global__ void finalize_k(const float* __restrict__ sum_sq, const int* __restrict__ hist,
                           float* __restrict__ loss_out, float* __restrict__ perp_out)
{
  if (threadIdx.x == 0) {
    float mse = sum_sq[0] / (float)NELEM;
    loss_out[0] = 1.25f * mse;
    float ent = 0.f;
    for (int k = 0; k < 64; ++k) {
      float p = (float)hist[k] / (float)NPOS;
      ent += p * logf(p + 1e-10f);
    }
    perp_out[0] = expf(-ent);
  }
}

// ---------------------------------------------------------------------------
extern "C" void kernel_launch(void* const* d_in, const int* in_sizes, int n_in,
                              void* d_out, int out_size, void* d_ws, size_t ws_size,
                              hipStream_t stream)
{
  const float* x        = (const float*)d_in[0];
  const float* enc_c1_w = (const float*)d_in[1];
  const float* enc_c1_b = (const float*)d_in[2];
  const float* enc_c2_w = (const float*)d_in[3];
  const float* enc_c2_b = (const float*)d_in[4];
  const float* enc_c3_w = (const float*)d_in[5];
  const float* enc_c3_b = (const float*)d_in[6];
  const float* enc_r1_w = (const float*)d_in[7];
  const float* enc_r2_w = (const float*)d_in[8];
  const float* vqc_w    = (const float*)d_in[9];
  const float* vqc_b    = (const float*)d_in[10];
  const float* emb      = (const float*)d_in[11];
  const float* dec_c1_w = (const float*)d_in[12];
  const float* dec_c1_b = (const float*)d_in[13];
  const float* dec_r1_w = (const float*)d_in[14];
  const float* dec_r2_w = (const float*)d_in[15];
  const float* dec_c2_w = (const float*)d_in[16];
  const float* dec_c2_b = (const float*)d_in[17];
  const float* dec_c3_w = (const float*)d_in[18];
  const float* dec_c3_b = (const float*)d_in[19];

  float* out      = (float*)d_out;
  float* loss_out = out;
  float* xre_out  = out + 1;
  float* perp_out = out + 1 + 2097152;
  float* qn_out   = out + 2 + 2097152;

  float* sum_sq = (float*)d_ws;
  int*   hist   = (int*)d_ws + 1;
  char*  pool   = (char*)d_ws + 1024;

  unsigned short* Wd   = (unsigned short*)(pool + 0);
  unsigned short* Weh  = (unsigned short*)(pool + 600000);
  unsigned short* Wel  = (unsigned short*)(pool + 1400000);
  unsigned short* Wvh  = (unsigned short*)(pool + 2121728);
  unsigned short* Wvl  = (unsigned short*)(pool + 2138112);
  unsigned short* Evh  = (unsigned short*)(pool + 2154496);
  unsigned short* Evl  = (unsigned short*)(pool + 2162688);
  float*          E2   = (float*)(pool + 2170880);
  unsigned short* E1ph = (unsigned short*)(pool + 2200000);
  unsigned short* E1pl = (unsigned short*)(pool + 73600000);
  unsigned short* B2h  = (unsigned short*)(pool + 145000000);
  unsigned short* B2l  = (unsigned short*)(pool + 181000000);
  unsigned short* R0h  = (unsigned short*)(pool + 2200000);
  unsigned short* R0l  = (unsigned short*)(pool + 38000000);
  unsigned short* Hh   = (unsigned short*)(pool + 74000000);
  unsigned short* Hl   = (unsigned short*)(pool + 92000000);
  unsigned short* S    = (unsigned short*)(pool + 110000000);
  unsigned short* X1h  = (unsigned short*)(pool + 145000000);
  unsigned short* X1l  = (unsigned short*)(pool + 181000000);
  unsigned short* X2h  = (unsigned short*)(pool + 2200000);
  unsigned short* X2l  = (unsigned short*)(pool + 38000000);
  unsigned short* Dq   = (unsigned short*)(pool + 217000000);
  unsigned short* Y1   = (unsigned short*)(pool + 145000000);
  unsigned short* Y2   = (unsigned short*)(pool + 181000000);
  unsigned short* P4   = (unsigned short*)(pool + 2200000);

  const int SS64  = 278784;
  const int SS128 = 557568;
  const int SSP4  = 1115136;

  hipLaunchKernelGGL(init_k, dim3(1), dim3(128), 0, stream, sum_sq, hist);
  hipLaunchKernelGGL(repack_k, dim3(1120), dim3(256), 0, stream,
                     dec_c1_w, dec_r1_w, dec_r2_w, dec_c2_w, Wd);
  hipLaunchKernelGGL(repack_enc_k, dim3(1408), dim3(256), 0, stream,
                     enc_c2_w, enc_c3_w, enc_r1_w, enc_r2_w, Weh, Wel);
  hipLaunchKernelGGL(repack_vq_k, dim3(48), dim3(256), 0, stream,
                     vqc_w, emb, Wvh, Wvl, Evh, Evl, E2);

  // rings group 1: E1 parity planes + B2 + Dq
  {
    RingArgs a;
    a.p[0] = E1ph; a.icl[0] = 6; a.H[0] = 66; a.planes[0] = 128;
    a.p[1] = E1pl; a.icl[1] = 6; a.H[1] = 66; a.planes[1] = 128;
    a.p[2] = B2h;  a.icl[2] = 7; a.H[2] = 66; a.planes[2] = 32;
    a.p[3] = B2l;  a.icl[3] = 7; a.H[3] = 66; a.planes[3] = 32;
    a.p[4] = Dq;   a.icl[4] = 6; a.H[4] = 66; a.planes[4] = 32;
    hipLaunchKernelGGL(rings_k, dim3(128, 5), dim3(256), 0, stream, a);
  }

  // ---- encoder ----
  hipLaunchKernelGGL(enc1_t, dim3(64, 4, 32), dim3(256), 0, stream,
                     x, enc_c1_w, enc_c1_b, E1ph, E1pl);
  hipLaunchKernelGGL(mfma_enc2p, dim3(512), dim3(256), 0, stream,
                     E1ph, E1pl, Weh, Wel, enc_c2_b, B2h, B2l);

  // rings group 2
  {
    RingArgs a;
    a.p[0] = R0h; a.icl[0] = 7; a.H[0] = 66; a.planes[0] = 32;
    a.p[1] = R0l; a.icl[1] = 7; a.H[1] = 66; a.planes[1] = 32;
    a.p[2] = Hh;  a.icl[2] = 6; a.H[2] = 66; a.planes[2] = 32;
    a.p[3] = Hl;  a.icl[3] = 6; a.H[3] = 66; a.planes[3] = 32;
    a.p[4] = S;   a.icl[4] = 6; a.H[4] = 66; a.planes[4] = 32;
    hipLaunchKernelGGL(rings_k, dim3(32, 5), dim3(256), 0, stream, a);
  }

  hipLaunchKernelGGL((mfma_enc3<128, 128, true, true>),
                     dim3(512), dim3(256), 0, stream,
                     B2h, B2l, Weh + 131072, Wel + 131072, enc_c3_b, R0h, R0l);

  // rings group 3
  {
    RingArgs a;
    a.p[0] = X1h; a.icl[0] = 7; a.H[0] = 66; a.planes[0] = 32;
    a.p[1] = X1l; a.icl[1] = 7; a.H[1] = 66; a.planes[1] = 32;
    a.p[2] = nullptr; a.icl[2] = 0; a.H[2] = 2; a.planes[2] = 0;
    a.p[3] = nullptr; a.icl[3] = 0; a.H[3] = 2; a.planes[3] = 0;
    a.p[4] = nullptr; a.icl[4] = 0; a.H[4] = 2; a.planes[4] = 0;
    hipLaunchKernelGGL(rings_k, dim3(32, 2), dim3(256), 0, stream, a);
  }

  hipLaunchKernelGGL((mfma_enc3<128, 64, false, true>),
                     dim3(512), dim3(256), 0, stream,
                     R0h, R0l, Weh + 278528, Wel + 278528, nullptr, Hh, Hl);
  hipLaunchKernelGGL((mfma_enc1x1<64, 128, true>),
                     dim3(512), dim3(256), 0, stream,
                     Hh, Hl, Weh + 352256, Wel + 352256, R0h, R0l, X1h, X1l);

  // rings group 4
  {
    RingArgs a;
    a.p[0] = X2h; a.icl[0] = 7; a.H[0] = 66; a.planes[0] = 32;
    a.p[1] = X2l; a.icl[1] = 7; a.H[1] = 66; a.planes[1] = 32;
    a.p[2] = nullptr; a.icl[2] = 0; a.H[2] = 2; a.planes[2] = 0;
    a.p[3] = nullptr; a.icl[3] = 0; a.H[3] = 2; a.planes[3] = 0;
    a.p[4] = nullptr; a.icl[4] = 0; a.H[4] = 2; a.planes[4] = 0;
    hipLaunchKernelGGL(rings_k, dim3(32, 2), dim3(256), 0, stream, a);
  }

  hipLaunchKernelGGL((mfma_enc3<128, 64, false, true>),
                     dim3(512), dim3(256), 0, stream,
                     X1h, X1l, Weh + 278528, Wel + 278528, nullptr, Hh, Hl);
  hipLaunchKernelGGL((mfma_enc1x1<64, 128, true>),
                     dim3(512), dim3(256), 0, stream,
                     Hh, Hl, Weh + 352256, Wel + 352256, X1h, X1l, X2h, X2l);

  // ---- VQ on MFMA ----
  hipLaunchKernelGGL(vq_mfma, dim3(64, 1, 32), dim3(256), 0, stream,
                     X2h, X2l, Wvh, Wvl, Evh, Evl, emb, E2, vqc_b,
                     qn_out, Dq, sum_sq, hist);

  // rings group 5: decoder regions
  {
    RingArgs a;
    a.p[0] = Y1;  a.icl[0] = 7; a.H[0] = 66; a.planes[0] = 32;
    a.p[1] = Y2;  a.icl[1] = 7; a.H[1] = 66; a.planes[1] = 32;
    a.p[2] = P4;  a.icl[2] = 6; a.H[2] = 66; a.planes[2] = 128;
    a.p[3] = nullptr; a.icl[3] = 0; a.H[3] = 2; a.planes[3] = 0;
    a.p[4] = nullptr; a.icl[4] = 0; a.H[4] = 2; a.planes[4] = 0;
    hipLaunchKernelGGL(rings_k, dim3(128, 3), dim3(256), 0, stream, a);
  }

  // ---- decoder (bf16 MFMA; 3x3 via LDS-staged kernel) ----
  hipLaunchKernelGGL((mfma_dec3<64, 128, true, true>),
                     dim3(512), dim3(256), 0, stream,
                     Dq, Wd, dec_c1_b, Y1);
  hipLaunchKernelGGL((mfma_dec3<128, 64, false, true>),
                     dim3(512), dim3(256), 0, stream,
                     Y1, Wd + 73728, nullptr, S);
  hipLaunchKernelGGL((mfma_conv<64, 128, 2, false, true, true>),
                     dim3(512), dim3(256), 0, stream,
                     S, Wd + 147456, nullptr, Y1, Y2, SS64, SS128);
  hipLaunchKernelGGL((mfma_dec3<128, 64, false, true>),
                     dim3(512), dim3(256), 0, stream,
                     Y2, Wd + 73728, nullptr, S);
  hipLaunchKernelGGL((mfma_conv<64, 128, 2, false, true, true>),
                     dim3(512), dim3(256), 0, stream,
                     S, Wd + 147456, nullptr, Y2, Y1, SS64, SS128);

  // dec_c2: 4 parities folded into the swizzled grid
  hipLaunchKernelGGL((mfma_conv<128, 64, 1, true, false, true>),
                     dim3(2048), dim3(256), 0, stream,
                     Y1, Wd + 155648, dec_c2_b, nullptr, P4, SS128, SSP4);

  hipLaunchKernelGGL(dec3_t, dim3(64, 1, 32), dim3(256), 0, stream,
                     P4, dec_c3_w, dec_c3_b, xre_out);

  hipLaunchKernelGGL(finalize_k, dim3(1), dim3(64), 0, stream,
                     sum_sq, hist, loss_out, perp_out);
}